// Round 5
// baseline (561.990 us; speedup 1.0000x reference)
//
#include <hip/hip_runtime.h>
#include <math.h>

#define B_ 32
#define N_ 1024
#define C_ 384
#define H_ 1024
#define NRES 20
#define NTAB 21
#define M_TOTAL (B_*N_)   // 32768
#define BK 32
#define KS 4              // GEMM3 K-splits

typedef __attribute__((ext_vector_type(8))) short bf16x8;
typedef __attribute__((ext_vector_type(4))) float f32x4;

#define GLOAD_LDS(gptr, lptr) \
    __builtin_amdgcn_global_load_lds( \
        (const __attribute__((address_space(1))) void*)(gptr), \
        (__attribute__((address_space(3))) void*)(lptr), 16, 0, 0)

__device__ inline short bf16_rne(float v) {
    unsigned u = __float_as_uint(v);
    unsigned r = u + 0x7fffu + ((u >> 16) & 1u);
    return (short)(r >> 16);
}
// v ~= hi + lo, each bf16 (RNE). ~16 mantissa bits captured.
__device__ inline void split2(float v, short& h, short& l) {
    unsigned u = __float_as_uint(v);
    unsigned r = (u + 0x7fffu + ((u >> 16) & 1u)) & 0xffff0000u;
    h = (short)(r >> 16);
    l = bf16_rne(v - __uint_as_float(r));
}

// ---------------- LN + split: one wave per row, full M ----------------
__global__ __launch_bounds__(256) void ln_split_kernel(const float* __restrict__ act,
                                                       const float* __restrict__ lng,
                                                       const float* __restrict__ lnb,
                                                       short* __restrict__ Xh,
                                                       short* __restrict__ Xl) {
    int wave = threadIdx.x >> 6;
    int lane = threadIdx.x & 63;
    int row  = blockIdx.x * 4 + wave;
    const float* x = act + (size_t)row * C_;
    float v[6];
    float s = 0.f;
#pragma unroll
    for (int i = 0; i < 6; i++) { v[i] = x[lane + i*64]; s += v[i]; }
#pragma unroll
    for (int off = 32; off > 0; off >>= 1) s += __shfl_xor(s, off, 64);
    float mu = s * (1.0f/384.0f);
    float vs = 0.f;
#pragma unroll
    for (int i = 0; i < 6; i++) { float d = v[i]-mu; vs += d*d; }
#pragma unroll
    for (int off = 32; off > 0; off >>= 1) vs += __shfl_xor(vs, off, 64);
    float rstd = 1.0f / sqrtf(vs * (1.0f/384.0f) + 1e-5f);
#pragma unroll
    for (int i = 0; i < 6; i++) {
        int col = lane + i*64;
        float y = (v[i] - mu) * rstd * lng[col] + lnb[col];
        short h, l; split2(y, h, l);
        Xh[(size_t)row * C_ + col] = h;
        Xl[(size_t)row * C_ + col] = l;
    }
}

// ---------------- weight transpose + split-bf16 convert ----------------
__global__ __launch_bounds__(256) void conv_w_kernel(const float* __restrict__ w,
                                                     short* __restrict__ th,
                                                     short* __restrict__ tl,
                                                     int K, int N, int Npad) {
    __shared__ float t[32][33];
    int n0 = blockIdx.x * 32, k0 = blockIdx.y * 32;
    int tx = threadIdx.x & 31, ty = threadIdx.x >> 5;
#pragma unroll
    for (int i = ty; i < 32; i += 8) {
        int k = k0 + i, n = n0 + tx;
        t[i][tx] = (n < N) ? w[(size_t)k * N + n] : 0.f;
    }
    __syncthreads();
#pragma unroll
    for (int i = ty; i < 32; i += 8) {
        int n = n0 + i, k = k0 + tx;
        short h, l; split2(t[tx][i], h, l);
        th[(size_t)n * K + k] = h;
        tl[(size_t)n * K + k] = l;
    }
}

// ---------------- presplit GEMM: 256x256, 8 waves, balanced-read pipeline -------
// v5 = R3's 16x16 core (0 bank conflicts) + balanced 6-read phases + unroll-2.
// Per-CU per-K-step budget: MFMA 3725 cyc; LDS reads 24/wave. v3 bunched them
// 4/8/0/12 -> ph3's burst (~1150cyc) exceeded its MFMA cover (931cyc). v5
// spreads 6/6/6/6 (576cyc each, fits) with every read >=1 phase ahead:
//  ph0: [STAGE8 t+1]; read bB,aB0 (cur);  MFMA aA.bA   (aA,bA: preloaded)
//  ph1: read aB1-3 (cur);                 MFMA aA.bB   (bB: ph0)
//       vmcnt(0); barrier; sched_barrier  <- tile t+1 resident for all waves
//  ph2: read aA'0-2 (nxt);                MFMA aB.bA   (aB: ph0/ph1)
//  ph3: read aA'3,bA' (nxt);              MFMA aB.bB
// Unroll-2 makes cur/nxt literal -> ds_read offsets fold to immediates (VALU cut).
// Hazards: DMA->nxt (ph0@t) is >=3 barriers after last cur-reads of that buffer
// (ph1@t-1); nxt preloads (ph2/ph3) follow the all-wave vmcnt(0)+barrier+SB.
// grid: (chunkM/256, N/256), 512 threads. NT must be even (K=384,1024 ok).
__global__ __launch_bounds__(512, 2) void presplit_gemm256(
    const short* __restrict__ Ahg, const short* __restrict__ Alg,
    const short* __restrict__ BTh, const short* __restrict__ BTl,
    const float* __restrict__ bias,
    short* __restrict__ Ch, short* __restrict__ Cl,
    int K, int ldc)
{
    __shared__ short P[4][2][256][32];   // planes {Ah,Al,Bh,Bl} x dbuf, 128 KiB
    const int BUFS = 256*32;             // shorts per buffer within a plane
    int tid = threadIdx.x;
    int m0 = blockIdx.x * 256;
    int n0 = blockIdx.y * 256;
    int lane = tid & 63, wv = tid >> 6;
    int wr = wv >> 2, wc = wv & 3;       // wave grid 2M x 4N -> wave tile 128x64
    int fm = lane & 15, kg = lane >> 4;

    // staging role: wave wv stages plane (wv>>1), row-half (wv&1): 8 DMAs/step
    int pl = wv >> 1, hf = wv & 1;
    const short* gsrc = (pl == 0) ? Ahg : (pl == 1) ? Alg : (pl == 2) ? BTh : BTl;
    int base = (pl < 2) ? m0 : n0;
    // lane l -> LDS slot (row16=l>>2, cb=l&3); fetch global cb ^ swz(row16)
    int swcb = (lane & 3) ^ ((lane >> 3) & 3);
    const short* gp = gsrc + (size_t)(base + hf*128 + (lane >> 2)) * K + swcb * 8;
    short* lpl = &P[pl][0][0][0] + hf * (128*32);

    // swizzled read col-offset (shorts); identical for all frag rows since
    // (row>>1)&3 == (fm>>1)&3 for row = 16*q + fm.
    int sz = (kg ^ ((fm >> 1) & 3)) * 8;
    const short* raH = &P[0][0][wr*128 + fm][0] + sz;
    const short* raL = &P[1][0][wr*128 + fm][0] + sz;
    const short* rbH = &P[2][0][wc*64  + fm][0] + sz;
    const short* rbL = &P[3][0][wc*64  + fm][0] + sz;

#define STAGE8(bsel, koff) \
    { _Pragma("unroll") \
      for (int c = 0; c < 8; c++) \
          GLOAD_LDS(gp + (size_t)(c*16) * K + (koff), lpl + (bsel)*BUFS + c*512); }

#define TRIPLE(ai, aj, AH, AL, BH, BL) { \
    f32x4 cc = acc[ai][aj]; \
    cc = __builtin_amdgcn_mfma_f32_16x16x32_bf16(AL, BH, cc, 0, 0, 0); \
    cc = __builtin_amdgcn_mfma_f32_16x16x32_bf16(AH, BL, cc, 0, 0, 0); \
    cc = __builtin_amdgcn_mfma_f32_16x16x32_bf16(AH, BH, cc, 0, 0, 0); \
    acc[ai][aj] = cc; }

    f32x4 acc[8][4] = {};
    const int NT = K / BK;

    bf16x8 aAh[4], aAl[4], aBh[4], aBl[4];
    bf16x8 bAh[2], bAl[2], bBh[2], bBl[2];

    // prologue: stage tile 0 into buffer 0, drain, preload aA(0), bA(0)
    STAGE8(0, 0);
    asm volatile("s_waitcnt vmcnt(0)" ::: "memory");
    __builtin_amdgcn_s_barrier();
    __builtin_amdgcn_sched_barrier(0);
#pragma unroll
    for (int i = 0; i < 4; i++) {
        aAh[i] = *(const bf16x8*)(raH + i*512);
        aAl[i] = *(const bf16x8*)(raL + i*512);
    }
#pragma unroll
    for (int j = 0; j < 2; j++) {
        bAh[j] = *(const bf16x8*)(rbH + j*512);
        bAl[j] = *(const bf16x8*)(rbL + j*512);
    }

#define STEP(CUR, NXT, T) { \
    const bool pf = (T) + 1 < NT; \
    const size_t koff = (size_t)((T) + 1) * BK; \
    /* ---- ph0: stage t+1; read bB, aB0 (cur); MFMA aA.bA ---- */ \
    if (pf) STAGE8(NXT, koff); \
    bBh[0] = *(const bf16x8*)(rbH + (CUR)*BUFS + 2*512); \
    bBl[0] = *(const bf16x8*)(rbL + (CUR)*BUFS + 2*512); \
    bBh[1] = *(const bf16x8*)(rbH + (CUR)*BUFS + 3*512); \
    bBl[1] = *(const bf16x8*)(rbL + (CUR)*BUFS + 3*512); \
    aBh[0] = *(const bf16x8*)(raH + (CUR)*BUFS + 4*512); \
    aBl[0] = *(const bf16x8*)(raL + (CUR)*BUFS + 4*512); \
    __builtin_amdgcn_s_setprio(1); \
    _Pragma("unroll") \
    for (int i = 0; i < 4; i++) \
        _Pragma("unroll") \
        for (int j = 0; j < 2; j++) TRIPLE(i, j, aAh[i], aAl[i], bAh[j], bAl[j]); \
    __builtin_amdgcn_s_setprio(0); \
    __builtin_amdgcn_s_barrier(); \
    /* ---- ph1: read aB1-3 (cur); MFMA aA.bB; counted drain ---- */ \
    _Pragma("unroll") \
    for (int i = 1; i < 4; i++) { \
        aBh[i] = *(const bf16x8*)(raH + (CUR)*BUFS + (4+i)*512); \
        aBl[i] = *(const bf16x8*)(raL + (CUR)*BUFS + (4+i)*512); \
    } \
    __builtin_amdgcn_s_setprio(1); \
    _Pragma("unroll") \
    for (int i = 0; i < 4; i++) \
        _Pragma("unroll") \
        for (int j = 0; j < 2; j++) TRIPLE(i, 2+j, aAh[i], aAl[i], bBh[j], bBl[j]); \
    __builtin_amdgcn_s_setprio(0); \
    asm volatile("s_waitcnt vmcnt(0)" ::: "memory"); \
    __builtin_amdgcn_s_barrier(); \
    __builtin_amdgcn_sched_barrier(0); \
    /* ---- ph2: read aA'0-2 (nxt); MFMA aB.bA ---- */ \
    if (pf) { \
        _Pragma("unroll") \
        for (int i = 0; i < 3; i++) { \
            aAh[i] = *(const bf16x8*)(raH + (NXT)*BUFS + i*512); \
            aAl[i] = *(const bf16x8*)(raL + (NXT)*BUFS + i*512); \
        } \
    } \
    __builtin_amdgcn_s_setprio(1); \
    _Pragma("unroll") \
    for (int i = 0; i < 4; i++) \
        _Pragma("unroll") \
        for (int j = 0; j < 2; j++) TRIPLE(4+i, j, aBh[i], aBl[i], bAh[j], bAl[j]); \
    __builtin_amdgcn_s_setprio(0); \
    __builtin_amdgcn_s_barrier(); \
    /* ---- ph3: read aA'3, bA' (nxt); MFMA aB.bB ---- */ \
    if (pf) { \
        aAh[3] = *(const bf16x8*)(raH + (NXT)*BUFS + 3*512); \
        aAl[3] = *(const bf16x8*)(raL + (NXT)*BUFS + 3*512); \
        _Pragma("unroll") \
        for (int j = 0; j < 2; j++) { \
            bAh[j] = *(const bf16x8*)(rbH + (NXT)*BUFS + j*512); \
            bAl[j] = *(const bf16x8*)(rbL + (NXT)*BUFS + j*512); \
        } \
    } \
    __builtin_amdgcn_s_setprio(1); \
    _Pragma("unroll") \
    for (int i = 0; i < 4; i++) \
        _Pragma("unroll") \
        for (int j = 0; j < 2; j++) TRIPLE(4+i, 2+j, aBh[i], aBl[i], bBh[j], bBl[j]); \
    __builtin_amdgcn_s_setprio(0); \
    __builtin_amdgcn_s_barrier(); \
}

    for (int t = 0; t < NT; t += 2) {
        STEP(0, 1, t);
        STEP(1, 0, t + 1);
    }
#undef STEP

#pragma unroll
    for (int i = 0; i < 8; i++)
#pragma unroll
        for (int j = 0; j < 4; j++) {
            int col = n0 + wc*64 + j*16 + fm;
            float bs = bias[col];
#pragma unroll
            for (int r = 0; r < 4; r++) {
                int row = m0 + wr*128 + i*16 + kg*4 + r;
                float v = fmaxf(acc[i][j][r] + bs, 0.f);
                short h, l; split2(v, h, l);
                Ch[(size_t)row * ldc + col] = h;
                Cl[(size_t)row * ldc + col] = l;
            }
        }
#undef STAGE8
#undef TRIPLE
}

// ---------------- GEMM3 split-K partial: 64-row x K/4 blocks -> f32 partials ----
// grid: (chunkM/64, KS), 256 threads. 4 blocks/CU, 8-step serial K-chain.
__global__ __launch_bounds__(256) void gemm3_partial(
    const short* __restrict__ Ahg, const short* __restrict__ Alg,   // H2 planes [M][1024]
    const short* __restrict__ BTh, const short* __restrict__ BTl,   // w3 planes [128][1024]
    float* __restrict__ Pbuf, int chunkM)
{
    __shared__ short Ah[2][64][32], Al[2][64][32];
    __shared__ short Bh[2][32][32], Bl[2][32][32];
    int tid = threadIdx.x;
    int m0 = blockIdx.x * 64;
    int ks = blockIdx.y;
    int lane = tid & 63, wv = tid >> 6;
    int wm = wv * 16;          // each wave computes 16 rows
    int fm = lane & 15, kg = lane >> 4;

    const short* gsrc = (wv == 0) ? Ahg : (wv == 1) ? Alg : (wv == 2) ? BTh : BTl;
    short* lb0 = (wv == 0) ? &Ah[0][0][0] : (wv == 1) ? &Al[0][0][0]
               : (wv == 2) ? &Bh[0][0][0] : &Bl[0][0][0];
    int pstride = (wv < 2) ? (64*32) : (32*32);
    int ncalls  = (wv < 2) ? 4 : 2;
    int base = (wv < 2) ? m0 : 0;
    int swcb = (lane & 3) ^ ((lane >> 3) & 3);
    const short* gp = gsrc + (size_t)(base + (lane >> 2)) * H_ + ks * (H_/KS) + swcb * 8;

    int saz = (kg ^ (((wm + fm) >> 1) & 3)) * 8;
    int sbz[2];
#pragma unroll
    for (int j = 0; j < 2; j++) sbz[j] = (kg ^ (((j*16 + fm) >> 1) & 3)) * 8;

    f32x4 acc[2] = {};
    const int NT = (H_/KS) / BK;   // 8

    // prologue: stage tile 0 into buffer 0
    for (int c = 0; c < ncalls; c++)
        GLOAD_LDS(gp + (size_t)(c * 16) * H_, lb0 + c * 512);

    for (int t = 0; t < NT; ++t) {
        __syncthreads();

        if (t + 1 < NT) {
            short* lb = lb0 + ((t + 1) & 1) * pstride;
            size_t k0n = (size_t)(t + 1) * BK;
            for (int c = 0; c < ncalls; c++)
                GLOAD_LDS(gp + (size_t)(c * 16) * H_ + k0n, lb + c * 512);
        }

        int cur = t & 1;
        bf16x8 a_h = *(bf16x8*)&Ah[cur][wm + fm][saz];
        bf16x8 a_l = *(bf16x8*)&Al[cur][wm + fm][saz];
        bf16x8 b_h[2], b_l[2];
#pragma unroll
        for (int j = 0; j < 2; j++) {
            b_h[j] = *(bf16x8*)&Bh[cur][j*16 + fm][sbz[j]];
            b_l[j] = *(bf16x8*)&Bl[cur][j*16 + fm][sbz[j]];
        }
#pragma unroll
        for (int j = 0; j < 2; j++) {
            f32x4 c = acc[j];
            c = __builtin_amdgcn_mfma_f32_16x16x32_bf16(a_l, b_h[j], c, 0, 0, 0);
            c = __builtin_amdgcn_mfma_f32_16x16x32_bf16(a_h, b_l[j], c, 0, 0, 0);
            c = __builtin_amdgcn_mfma_f32_16x16x32_bf16(a_h, b_h[j], c, 0, 0, 0);
            acc[j] = c;
        }
    }

#pragma unroll
    for (int j = 0; j < 2; j++)
#pragma unroll
        for (int r = 0; r < 4; r++)
            Pbuf[((size_t)ks * chunkM + m0 + wm + kg*4 + r) * 32 + j*16 + fm] = acc[j][r];
}

// ---------------- logits reduce: sum KS partials + bias, argmax, mask ----------
__global__ __launch_bounds__(256) void logits_reduce(
    const float* __restrict__ Pbuf, const float* __restrict__ b3,
    const int* __restrict__ fixed_mask, const int* __restrict__ seq_t,
    float* __restrict__ out_logits, float* __restrict__ seq_out,
    int* __restrict__ seq_int, int chunkM, int m0c)
{
    int lrow = blockIdx.x * 256 + threadIdx.x;
    int grow = m0c + lrow;
    float best = -1e30f; int bi = 0;
    float* lg = out_logits + (size_t)grow * NRES;
#pragma unroll
    for (int n = 0; n < NRES; n++) {
        float s = b3[n];
#pragma unroll
        for (int k = 0; k < KS; k++)
            s += Pbuf[((size_t)k * chunkM + lrow) * 32 + n];
        lg[n] = s;
        if (s > best) { best = s; bi = n; }
    }
    int fmk = fixed_mask[grow];
    int sv = fmk ? seq_t[grow] : bi;
    seq_int[grow] = sv;
    seq_out[grow] = (float)sv;
}

// ---------------- geometry: one thread per (b,n) ----------------
__global__ __launch_bounds__(128) void geom_kernel(
    const float* __restrict__ angles, const float* __restrict__ rigids,
    const int* __restrict__ seq0i, const int* __restrict__ residx,
    const float* __restrict__ dframes, const int* __restrict__ gidx,
    const float* __restrict__ a14m, const float* __restrict__ a37m,
    const float* __restrict__ litp,
    float* __restrict__ out_pred, float* __restrict__ out_final,
    float* __restrict__ out_m14, float* __restrict__ out_m37)
{
    __shared__ float sdf[NTAB*8*16];
    __shared__ int   sgi[NTAB*14];
    __shared__ float sm14[NTAB*14];
    __shared__ float sm37[NTAB*37];
    __shared__ float slit[NTAB*14*3];
    __shared__ float predL[128][43];

    for (int i = threadIdx.x; i < NTAB*128; i += 128) sdf[i] = dframes[i];
    for (int i = threadIdx.x; i < NTAB*14; i += 128) { sgi[i] = gidx[i]; sm14[i] = a14m[i]; }
    for (int i = threadIdx.x; i < NTAB*37; i += 128) sm37[i] = a37m[i];
    for (int i = threadIdx.x; i < NTAB*42; i += 128) slit[i] = litp[i];
    __syncthreads();

    int p = blockIdx.x * 128 + threadIdx.x;
    int s = seq0i[p];

    const float* rg = rigids + (size_t)p * 7;
    float qw = rg[0], qx = rg[1], qy = rg[2], qz = rg[3];
    float tbx = rg[4], tby = rg[5], tbz = rg[6];
    float qn = 1.0f / sqrtf(qw*qw + qx*qx + qy*qy + qz*qz + 1e-8f);
    qw *= qn; qx *= qn; qy *= qn; qz *= qn;
    float rb[9];
    rb[0] = 1.f - 2.f*(qy*qy + qz*qz); rb[1] = 2.f*(qx*qy - qw*qz); rb[2] = 2.f*(qx*qz + qw*qy);
    rb[3] = 2.f*(qx*qy + qw*qz); rb[4] = 1.f - 2.f*(qx*qx + qz*qz); rb[5] = 2.f*(qy*qz - qw*qx);
    rb[6] = 2.f*(qx*qz - qw*qy); rb[7] = 2.f*(qy*qz + qw*qx); rb[8] = 1.f - 2.f*(qx*qx + qy*qy);

    float fr[8][9], ft[8][3];
    const float* ang = angles + (size_t)p * 14;
#pragma unroll
    for (int g = 0; g < 8; g++) {
        const float* df = &sdf[(s*8 + g)*16];
        float c, sn;
        if (g == 0) { c = 1.f; sn = 0.f; }
        else { sn = ang[(g-1)*2 + 0]; c = ang[(g-1)*2 + 1]; }
#pragma unroll
        for (int i = 0; i < 3; i++) {
            float d0 = df[i*4+0], d1 = df[i*4+1], d2 = df[i*4+2];
            fr[g][i*3+0] = d0;
            fr[g][i*3+1] = d1*c + d2*sn;
            fr[g][i*3+2] = d2*c - d1*sn;
            ft[g][i] = df[i*4+3];
        }
    }
#pragma unroll
    for (int g = 5; g <= 7; g++) {
        float r[9], t[3];
        const float* r1 = fr[g-1];
        const float* t1 = ft[g-1];
#pragma unroll
        for (int i = 0; i < 3; i++) {
#pragma unroll
            for (int j = 0; j < 3; j++)
                r[i*3+j] = r1[i*3+0]*fr[g][0*3+j] + r1[i*3+1]*fr[g][1*3+j] + r1[i*3+2]*fr[g][2*3+j];
            t[i] = r1[i*3+0]*ft[g][0] + r1[i*3+1]*ft[g][1] + r1[i*3+2]*ft[g][2] + t1[i];
        }
#pragma unroll
        for (int i = 0; i < 9; i++) fr[g][i] = r[i];
#pragma unroll
        for (int i = 0; i < 3; i++) ft[g][i] = t[i];
    }
#pragma unroll
    for (int g = 0; g < 8; g++) {
        float r[9], t[3];
#pragma unroll
        for (int i = 0; i < 3; i++) {
#pragma unroll
            for (int j = 0; j < 3; j++)
                r[i*3+j] = rb[i*3+0]*fr[g][0*3+j] + rb[i*3+1]*fr[g][1*3+j] + rb[i*3+2]*fr[g][2*3+j];
            t[i] = rb[i*3+0]*ft[g][0] + rb[i*3+1]*ft[g][1] + rb[i*3+2]*ft[g][2];
        }
#pragma unroll
        for (int i = 0; i < 9; i++) fr[g][i] = r[i];
        ft[g][0]=t[0]+tbx; ft[g][1]=t[1]+tby; ft[g][2]=t[2]+tbz;
    }
#pragma unroll
    for (int g = 0; g < 8; g++) {
#pragma unroll
        for (int a = 0; a < 14; a++) {
            if (sgi[s*14 + a] == g) {
                float m  = sm14[s*14 + a];
                float lx = slit[(s*14 + a)*3 + 0];
                float ly = slit[(s*14 + a)*3 + 1];
                float lz = slit[(s*14 + a)*3 + 2];
                float px = (fr[g][0]*lx + fr[g][1]*ly + fr[g][2]*lz + ft[g][0]) * m;
                float py = (fr[g][3]*lx + fr[g][4]*ly + fr[g][5]*lz + ft[g][1]) * m;
                float pz = (fr[g][6]*lx + fr[g][7]*ly + fr[g][8]*lz + ft[g][2]) * m;
                predL[threadIdx.x][a*3+0] = px;
                predL[threadIdx.x][a*3+1] = py;
                predL[threadIdx.x][a*3+2] = pz;
                out_pred[((size_t)p*14 + a)*3 + 0] = px;
                out_pred[((size_t)p*14 + a)*3 + 1] = py;
                out_pred[((size_t)p*14 + a)*3 + 2] = pz;
            }
        }
    }
#pragma unroll
    for (int a = 0; a < 14; a++) out_m14[(size_t)p*14 + a] = sm14[s*14 + a];

    const int* idx = residx + (size_t)p * 37;
#pragma unroll
    for (int a = 0; a < 37; a++) {
        int id = idx[a];
        out_final[((size_t)p*37 + a)*3 + 0] = predL[threadIdx.x][id*3+0];
        out_final[((size_t)p*37 + a)*3 + 1] = predL[threadIdx.x][id*3+1];
        out_final[((size_t)p*37 + a)*3 + 2] = predL[threadIdx.x][id*3+2];
        out_m37[(size_t)p*37 + a] = sm37[s*37 + a];
    }
}

extern "C" void kernel_launch(void* const* d_in, const int* in_sizes, int n_in,
                              void* d_out, int out_size, void* d_ws, size_t ws_size,
                              hipStream_t stream) {
    const float* act        = (const float*)d_in[0];
    const float* angles     = (const float*)d_in[1];
    const float* rigids     = (const float*)d_in[2];
    const int*   fixed_mask = (const int*)d_in[3];
    const int*   seq_t      = (const int*)d_in[4];
    const int*   residx     = (const int*)d_in[5];
    const float* lng        = (const float*)d_in[6];
    const float* lnb        = (const float*)d_in[7];
    const float* w1         = (const float*)d_in[8];
    const float* b1         = (const float*)d_in[9];
    const float* w2         = (const float*)d_in[10];
    const float* b2         = (const float*)d_in[11];
    const float* w3         = (const float*)d_in[12];
    const float* b3         = (const float*)d_in[13];
    const float* dfr        = (const float*)d_in[14];
    const int*   gidx       = (const int*)d_in[15];
    const float* a14m       = (const float*)d_in[16];
    const float* a37m       = (const float*)d_in[17];
    const float* litp       = (const float*)d_in[18];

    float* out        = (float*)d_out;
    float* out_logits = out;
    float* out_seq    = out_logits + (size_t)M_TOTAL * NRES;
    float* out_pred   = out_seq    + (size_t)M_TOTAL;
    float* out_final  = out_pred   + (size_t)M_TOTAL * 42;
    float* out_m14    = out_final  + (size_t)M_TOTAL * 111;
    float* out_m37    = out_m14    + (size_t)M_TOTAL * 14;

    char* wsp = (char*)d_ws;
    int*   seq0i = (int*)wsp;   wsp += (size_t)M_TOTAL * sizeof(int);
    short* w1h   = (short*)wsp; wsp += (size_t)H_ * C_ * sizeof(short);
    short* w1l   = (short*)wsp; wsp += (size_t)H_ * C_ * sizeof(short);
    short* w2h   = (short*)wsp; wsp += (size_t)H_ * H_ * sizeof(short);
    short* w2l   = (short*)wsp; wsp += (size_t)H_ * H_ * sizeof(short);
    short* w3h   = (short*)wsp; wsp += (size_t)128 * H_ * sizeof(short);
    short* w3l   = (short*)wsp; wsp += (size_t)128 * H_ * sizeof(short);
    short* Xh    = (short*)wsp; wsp += (size_t)M_TOTAL * C_ * sizeof(short);
    short* Xl    = (short*)wsp; wsp += (size_t)M_TOTAL * C_ * sizeof(short);

    size_t fixed_bytes = (size_t)(wsp - (char*)d_ws);
    size_t per_row = 4ull * H_ * sizeof(short);   // H1h/H1l/H2h/H2l
    size_t avail = ws_size - fixed_bytes;
    int chunkM = 4096;
    if (avail >= (size_t)M_TOTAL * per_row)      chunkM = M_TOTAL;
    else if (avail >= 16384ull * per_row)        chunkM = 16384;
    else if (avail >= 8192ull * per_row)         chunkM = 8192;

    short* H1h = (short*)wsp; wsp += (size_t)chunkM * H_ * sizeof(short);
    short* H1l = (short*)wsp; wsp += (size_t)chunkM * H_ * sizeof(short);
    short* H2h = (short*)wsp; wsp += (size_t)chunkM * H_ * sizeof(short);
    short* H2l = (short*)wsp;

    // GEMM3 partial buffer reuses H1h (dead after GEMM2 reads it):
    // KS*chunkM*32*4 B = chunkM*512 B  <=  H1h = chunkM*2048 B.
    float* Pbuf = (float*)H1h;

    conv_w_kernel<<<dim3(H_/32, C_/32), 256, 0, stream>>>(w1, w1h, w1l, C_, H_, H_);
    conv_w_kernel<<<dim3(H_/32, H_/32), 256, 0, stream>>>(w2, w2h, w2l, H_, H_, H_);
    conv_w_kernel<<<dim3(128/32, H_/32), 256, 0, stream>>>(w3, w3h, w3l, H_, NRES, 128);

    ln_split_kernel<<<M_TOTAL/4, 256, 0, stream>>>(act, lng, lnb, Xh, Xl);

    for (int c = 0; c < M_TOTAL / chunkM; c++) {
        int m0 = c * chunkM;
        // GEMM1: LN'd act planes @ w1 (K=384)
        presplit_gemm256<<<dim3(chunkM/256, H_/256), 512, 0, stream>>>(
            Xh + (size_t)m0 * C_, Xl + (size_t)m0 * C_, w1h, w1l, b1, H1h, H1l, C_, H_);
        // GEMM2: H1 @ w2 (K=1024)
        presplit_gemm256<<<dim3(chunkM/256, H_/256), 512, 0, stream>>>(
            H1h, H1l, w2h, w2l, b2, H2h, H2l, H_, H_);
        // GEMM3 split-K partials (H1h is dead now -> reused as Pbuf)
        gemm3_partial<<<dim3(chunkM/64, KS), 256, 0, stream>>>(
            H2h, H2l, w3h, w3l, Pbuf, chunkM);
        // reduce: bias + argmax + mask
        logits_reduce<<<chunkM/256, 256, 0, stream>>>(
            Pbuf, b3, fixed_mask, seq_t, out_logits, out_seq, seq0i, chunkM, m0);
    }

    geom_kernel<<<M_TOTAL/128, 128, 0, stream>>>(angles, rigids, seq0i, residx,
                                                 dfr, gidx, a14m, a37m, litp,
                                                 out_pred, out_final, out_m14, out_m37);
}

// Round 6
// 468.033 us; speedup vs baseline: 1.2007x; 1.2007x over previous
//
#include <hip/hip_runtime.h>
#include <math.h>

#define B_ 32
#define N_ 1024
#define C_ 384
#define H_ 1024
#define NRES 20
#define NTAB 21
#define M_TOTAL (B_*N_)   // 32768
#define BK 32

typedef __attribute__((ext_vector_type(8))) short bf16x8;
typedef __attribute__((ext_vector_type(4))) float f32x4;

#define GLOAD_LDS(gptr, lptr) \
    __builtin_amdgcn_global_load_lds( \
        (const __attribute__((address_space(1))) void*)(gptr), \
        (__attribute__((address_space(3))) void*)(lptr), 16, 0, 0)

__device__ inline short bf16_rne(float v) {
    unsigned u = __float_as_uint(v);
    unsigned r = u + 0x7fffu + ((u >> 16) & 1u);
    return (short)(r >> 16);
}
// v ~= hi + lo, each bf16 (RNE). ~16 mantissa bits captured.
__device__ inline void split2(float v, short& h, short& l) {
    unsigned u = __float_as_uint(v);
    unsigned r = (u + 0x7fffu + ((u >> 16) & 1u)) & 0xffff0000u;
    h = (short)(r >> 16);
    l = bf16_rne(v - __uint_as_float(r));
}

// ---------------- LN + split: one wave per row, full M ----------------
__global__ __launch_bounds__(256) void ln_split_kernel(const float* __restrict__ act,
                                                       const float* __restrict__ lng,
                                                       const float* __restrict__ lnb,
                                                       short* __restrict__ Xh,
                                                       short* __restrict__ Xl) {
    int wave = threadIdx.x >> 6;
    int lane = threadIdx.x & 63;
    int row  = blockIdx.x * 4 + wave;
    const float* x = act + (size_t)row * C_;
    float v[6];
    float s = 0.f;
#pragma unroll
    for (int i = 0; i < 6; i++) { v[i] = x[lane + i*64]; s += v[i]; }
#pragma unroll
    for (int off = 32; off > 0; off >>= 1) s += __shfl_xor(s, off, 64);
    float mu = s * (1.0f/384.0f);
    float vs = 0.f;
#pragma unroll
    for (int i = 0; i < 6; i++) { float d = v[i]-mu; vs += d*d; }
#pragma unroll
    for (int off = 32; off > 0; off >>= 1) vs += __shfl_xor(vs, off, 64);
    float rstd = 1.0f / sqrtf(vs * (1.0f/384.0f) + 1e-5f);
#pragma unroll
    for (int i = 0; i < 6; i++) {
        int col = lane + i*64;
        float y = (v[i] - mu) * rstd * lng[col] + lnb[col];
        short h, l; split2(y, h, l);
        Xh[(size_t)row * C_ + col] = h;
        Xl[(size_t)row * C_ + col] = l;
    }
}

// ---------------- weight transpose + split-bf16 convert ----------------
__global__ __launch_bounds__(256) void conv_w_kernel(const float* __restrict__ w,
                                                     short* __restrict__ th,
                                                     short* __restrict__ tl,
                                                     int K, int N, int Npad) {
    __shared__ float t[32][33];
    int n0 = blockIdx.x * 32, k0 = blockIdx.y * 32;
    int tx = threadIdx.x & 31, ty = threadIdx.x >> 5;
#pragma unroll
    for (int i = ty; i < 32; i += 8) {
        int k = k0 + i, n = n0 + tx;
        t[i][tx] = (n < N) ? w[(size_t)k * N + n] : 0.f;
    }
    __syncthreads();
#pragma unroll
    for (int i = ty; i < 32; i += 8) {
        int n = n0 + i, k = k0 + tx;
        short h, l; split2(t[tx][i], h, l);
        th[(size_t)n * K + k] = h;
        tl[(size_t)n * K + k] = l;
    }
}

// ---------------- presplit GEMM: 256x256 tile, 8 waves, 4-phase counted-vmcnt ----
// R2 schedule (best measured total) + T1 XCD-aware bijective block swizzle.
// Per K-step (BK=32), 4 phases of {2 stage-DMAs + ds_reads -> s_barrier ->
// setprio(1) 24 MFMAs setprio(0) -> s_barrier}. vmcnt(2) counted once per step.
// Swizzle (m204 bijective): HW dispatches original bid round-robin to XCDs;
// remap so each XCD owns a run of consecutive tiles (x-fastest -> shared
// B-panel stays in that XCD's L2). Identity when nwg<8; bijective always.
// grid: (chunkM/256, N/256), 512 threads.
__global__ __launch_bounds__(512, 2) void presplit_gemm256(
    const short* __restrict__ Ahg, const short* __restrict__ Alg,
    const short* __restrict__ BTh, const short* __restrict__ BTl,
    const float* __restrict__ bias,
    short* __restrict__ Ch, short* __restrict__ Cl,
    int K, int ldc)
{
    __shared__ short P[4][2][256][32];   // planes {Ah,Al,Bh,Bl} x dbuf, 128 KiB
    const int BUFS = 256*32;             // shorts per buffer within a plane
    int tid = threadIdx.x;

    // T1 XCD swizzle (bijective, m204): consecutive tiles -> same XCD
    int nx = gridDim.x;
    int nwg = nx * gridDim.y;
    int bid = blockIdx.y * nx + blockIdx.x;
    int q = nwg >> 3, r = nwg & 7;
    int xcd = bid & 7, loc = bid >> 3;
    int swz = (xcd < r) ? (xcd * (q + 1) + loc)
                        : (r * (q + 1) + (xcd - r) * q + loc);
    int m0 = (swz % nx) * 256;
    int n0 = (swz / nx) * 256;

    int lane = tid & 63, wv = tid >> 6;
    int wr = wv >> 2, wc = wv & 3;       // wave grid 2M x 4N -> wave tile 128x64
    int fm = lane & 15, kg = lane >> 4;

    // staging role: wave wv stages plane (wv>>1), row-half (wv&1): 8 DMAs/step
    int pl = wv >> 1, hf = wv & 1;
    const short* gsrc = (pl == 0) ? Ahg : (pl == 1) ? Alg : (pl == 2) ? BTh : BTl;
    int base = (pl < 2) ? m0 : n0;
    // lane l -> LDS slot (row16=l>>2, cb=l&3); fetch global cb ^ swz(row16)
    int swcb = (lane & 3) ^ ((lane >> 3) & 3);
    const short* gp = gsrc + (size_t)(base + hf*128 + (lane >> 2)) * K + swcb * 8;
    short* lpl = &P[pl][0][0][0] + hf * (128*32);

    // swizzled read col-offset (shorts); identical for all frag rows since
    // (row>>1)&3 == (fm>>1)&3 for row = 16*q + fm.
    int sz = (kg ^ ((fm >> 1) & 3)) * 8;
    const short* raH = &P[0][0][wr*128 + fm][0] + sz;
    const short* raL = &P[1][0][wr*128 + fm][0] + sz;
    const short* rbH = &P[2][0][wc*64  + fm][0] + sz;
    const short* rbL = &P[3][0][wc*64  + fm][0] + sz;

#define STAGE(c, bsel, koff) \
    GLOAD_LDS(gp + (size_t)((c)*16) * K + (koff), lpl + (bsel)*BUFS + (c)*512)

#define TRIPLE(ai, aj, AH, AL, BH, BL) { \
    f32x4 cc = acc[ai][aj]; \
    cc = __builtin_amdgcn_mfma_f32_16x16x32_bf16(AL, BH, cc, 0, 0, 0); \
    cc = __builtin_amdgcn_mfma_f32_16x16x32_bf16(AH, BL, cc, 0, 0, 0); \
    cc = __builtin_amdgcn_mfma_f32_16x16x32_bf16(AH, BH, cc, 0, 0, 0); \
    acc[ai][aj] = cc; }

    f32x4 acc[8][4] = {};
    const int NT = K / BK;

    // prologue: stage tile 0 into buffer 0
#pragma unroll
    for (int c = 0; c < 8; c++) STAGE(c, 0, 0);

    for (int t = 0; t < NT; ++t) {
        int cur = t & 1, nxt = cur ^ 1;
        size_t koff = (size_t)(t + 1) * BK;
        bool pf = (t + 1 < NT);

        bf16x8 a_h[4], a_l[4], b_h[4], b_l[4];

        // ---- phase 0: a0-3 + b0-1, MFMA i0-3 x j0-1 ----
        if (pf) {
            STAGE(0, nxt, koff); STAGE(1, nxt, koff);
            asm volatile("s_waitcnt vmcnt(2)" ::: "memory");
        } else {
            asm volatile("s_waitcnt vmcnt(0)" ::: "memory");
        }
        __builtin_amdgcn_s_barrier();
        __builtin_amdgcn_sched_barrier(0);
#pragma unroll
        for (int i = 0; i < 4; i++) {
            a_h[i] = *(const bf16x8*)(raH + cur*BUFS + i*512);
            a_l[i] = *(const bf16x8*)(raL + cur*BUFS + i*512);
        }
#pragma unroll
        for (int j = 0; j < 2; j++) {
            b_h[j] = *(const bf16x8*)(rbH + cur*BUFS + j*512);
            b_l[j] = *(const bf16x8*)(rbL + cur*BUFS + j*512);
        }
        __builtin_amdgcn_s_setprio(1);
#pragma unroll
        for (int i = 0; i < 4; i++)
#pragma unroll
            for (int j = 0; j < 2; j++) TRIPLE(i, j, a_h[i], a_l[i], b_h[j], b_l[j]);
        __builtin_amdgcn_s_setprio(0);
        __builtin_amdgcn_s_barrier();

        // ---- phase 1: b2-3, MFMA i0-3 x j2-3 ----
        if (pf) { STAGE(2, nxt, koff); STAGE(3, nxt, koff); }
#pragma unroll
        for (int j = 0; j < 2; j++) {
            b_h[2+j] = *(const bf16x8*)(rbH + cur*BUFS + (2+j)*512);
            b_l[2+j] = *(const bf16x8*)(rbL + cur*BUFS + (2+j)*512);
        }
        __builtin_amdgcn_s_barrier();
        __builtin_amdgcn_s_setprio(1);
#pragma unroll
        for (int i = 0; i < 4; i++)
#pragma unroll
            for (int j = 0; j < 2; j++) TRIPLE(i, 2+j, a_h[i], a_l[i], b_h[2+j], b_l[2+j]);
        __builtin_amdgcn_s_setprio(0);
        __builtin_amdgcn_s_barrier();

        // ---- phase 2: a4-7, MFMA i4-7 x j0-1 ----
        if (pf) { STAGE(4, nxt, koff); STAGE(5, nxt, koff); }
#pragma unroll
        for (int i = 0; i < 4; i++) {
            a_h[i] = *(const bf16x8*)(raH + cur*BUFS + (4+i)*512);
            a_l[i] = *(const bf16x8*)(raL + cur*BUFS + (4+i)*512);
        }
        __builtin_amdgcn_s_barrier();
        __builtin_amdgcn_s_setprio(1);
#pragma unroll
        for (int i = 0; i < 4; i++)
#pragma unroll
            for (int j = 0; j < 2; j++) TRIPLE(4+i, j, a_h[i], a_l[i], b_h[j], b_l[j]);
        __builtin_amdgcn_s_setprio(0);
        __builtin_amdgcn_s_barrier();

        // ---- phase 3: MFMA i4-7 x j2-3 ----
        if (pf) { STAGE(6, nxt, koff); STAGE(7, nxt, koff); }
        __builtin_amdgcn_s_barrier();
        __builtin_amdgcn_s_setprio(1);
#pragma unroll
        for (int i = 0; i < 4; i++)
#pragma unroll
            for (int j = 0; j < 2; j++) TRIPLE(4+i, 2+j, a_h[i], a_l[i], b_h[2+j], b_l[2+j]);
        __builtin_amdgcn_s_setprio(0);
        __builtin_amdgcn_s_barrier();
    }

#pragma unroll
    for (int i = 0; i < 8; i++)
#pragma unroll
        for (int j = 0; j < 4; j++) {
            int col = n0 + wc*64 + j*16 + fm;
            float bs = bias[col];
#pragma unroll
            for (int r2 = 0; r2 < 4; r2++) {
                int row = m0 + wr*128 + i*16 + kg*4 + r2;
                float v = fmaxf(acc[i][j][r2] + bs, 0.f);
                short h, l; split2(v, h, l);
                Ch[(size_t)row * ldc + col] = h;
                Cl[(size_t)row * ldc + col] = l;
            }
        }
#undef STAGE
#undef TRIPLE
}

// ---------------- GEMM3 fused: 64-row blocks, full-K, logits+argmax in-kernel ----
// Double-buffered single-barrier pipeline. grid: (chunkM/64).
__global__ __launch_bounds__(256) void gemm3_fused(
    const short* __restrict__ Ahg, const short* __restrict__ Alg,   // H2 planes [M][1024]
    const short* __restrict__ BTh, const short* __restrict__ BTl,   // w3 planes [128][1024]
    const float* __restrict__ b3,
    const int* __restrict__ fixed_mask, const int* __restrict__ seq_t,
    float* __restrict__ out_logits, float* __restrict__ seq_out,
    int* __restrict__ seq_int, int m0c)
{
    __shared__ short Ah[2][64][32], Al[2][64][32];
    __shared__ short Bh[2][32][32], Bl[2][32][32];
    __shared__ float slog[64][33];
    int tid = threadIdx.x;
    int m0 = blockIdx.x * 64;
    int lane = tid & 63, wv = tid >> 6;
    int wm = wv * 16;          // each wave computes 16 rows
    int fm = lane & 15, kg = lane >> 4;

    const short* gsrc = (wv == 0) ? Ahg : (wv == 1) ? Alg : (wv == 2) ? BTh : BTl;
    short* lb0 = (wv == 0) ? &Ah[0][0][0] : (wv == 1) ? &Al[0][0][0]
               : (wv == 2) ? &Bh[0][0][0] : &Bl[0][0][0];
    int pstride = (wv < 2) ? (64*32) : (32*32);
    int ncalls  = (wv < 2) ? 4 : 2;
    int base = (wv < 2) ? m0 : 0;
    int swcb = (lane & 3) ^ ((lane >> 3) & 3);
    const short* gp = gsrc + (size_t)(base + (lane >> 2)) * H_ + swcb * 8;

    int saz = (kg ^ (((wm + fm) >> 1) & 3)) * 8;
    int sbz[2];
#pragma unroll
    for (int j = 0; j < 2; j++) sbz[j] = (kg ^ (((j*16 + fm) >> 1) & 3)) * 8;

    f32x4 acc[2] = {};
    const int NT = H_ / BK;

    // prologue: stage tile 0 into buffer 0
    for (int c = 0; c < ncalls; c++)
        GLOAD_LDS(gp + (size_t)(c * 16) * H_, lb0 + c * 512);

    for (int t = 0; t < NT; ++t) {
        __syncthreads();

        if (t + 1 < NT) {
            short* lb = lb0 + ((t + 1) & 1) * pstride;
            size_t k0n = (size_t)(t + 1) * BK;
            for (int c = 0; c < ncalls; c++)
                GLOAD_LDS(gp + (size_t)(c * 16) * H_ + k0n, lb + c * 512);
        }

        int cur = t & 1;
        bf16x8 a_h = *(bf16x8*)&Ah[cur][wm + fm][saz];
        bf16x8 a_l = *(bf16x8*)&Al[cur][wm + fm][saz];
        bf16x8 b_h[2], b_l[2];
#pragma unroll
        for (int j = 0; j < 2; j++) {
            b_h[j] = *(bf16x8*)&Bh[cur][j*16 + fm][sbz[j]];
            b_l[j] = *(bf16x8*)&Bl[cur][j*16 + fm][sbz[j]];
        }
#pragma unroll
        for (int j = 0; j < 2; j++) {
            f32x4 c = acc[j];
            c = __builtin_amdgcn_mfma_f32_16x16x32_bf16(a_l, b_h[j], c, 0, 0, 0);
            c = __builtin_amdgcn_mfma_f32_16x16x32_bf16(a_h, b_l[j], c, 0, 0, 0);
            c = __builtin_amdgcn_mfma_f32_16x16x32_bf16(a_h, b_h[j], c, 0, 0, 0);
            acc[j] = c;
        }
    }

#pragma unroll
    for (int j = 0; j < 2; j++)
#pragma unroll
        for (int r = 0; r < 4; r++)
            slog[wm + kg*4 + r][j*16 + fm] = acc[j][r];
    __syncthreads();

    if (tid < 64) {
        int grow = m0c + m0 + tid;
        float best = -1e30f; int bi = 0;
        float* lg = out_logits + (size_t)grow * NRES;
#pragma unroll
        for (int n = 0; n < NRES; n++) {
            float s = slog[tid][n] + b3[n];
            lg[n] = s;
            if (s > best) { best = s; bi = n; }
        }
        int fmk = fixed_mask[grow];
        int s = fmk ? seq_t[grow] : bi;
        seq_int[grow] = s;
        seq_out[grow] = (float)s;
    }
}

// ---------------- geometry: one thread per (b,n) ----------------
__global__ __launch_bounds__(128) void geom_kernel(
    const float* __restrict__ angles, const float* __restrict__ rigids,
    const int* __restrict__ seq0i, const int* __restrict__ residx,
    const float* __restrict__ dframes, const int* __restrict__ gidx,
    const float* __restrict__ a14m, const float* __restrict__ a37m,
    const float* __restrict__ litp,
    float* __restrict__ out_pred, float* __restrict__ out_final,
    float* __restrict__ out_m14, float* __restrict__ out_m37)
{
    __shared__ float sdf[NTAB*8*16];
    __shared__ int   sgi[NTAB*14];
    __shared__ float sm14[NTAB*14];
    __shared__ float sm37[NTAB*37];
    __shared__ float slit[NTAB*14*3];
    __shared__ float predL[128][43];

    for (int i = threadIdx.x; i < NTAB*128; i += 128) sdf[i] = dframes[i];
    for (int i = threadIdx.x; i < NTAB*14; i += 128) { sgi[i] = gidx[i]; sm14[i] = a14m[i]; }
    for (int i = threadIdx.x; i < NTAB*37; i += 128) sm37[i] = a37m[i];
    for (int i = threadIdx.x; i < NTAB*42; i += 128) slit[i] = litp[i];
    __syncthreads();

    int p = blockIdx.x * 128 + threadIdx.x;
    int s = seq0i[p];

    const float* rg = rigids + (size_t)p * 7;
    float qw = rg[0], qx = rg[1], qy = rg[2], qz = rg[3];
    float tbx = rg[4], tby = rg[5], tbz = rg[6];
    float qn = 1.0f / sqrtf(qw*qw + qx*qx + qy*qy + qz*qz + 1e-8f);
    qw *= qn; qx *= qn; qy *= qn; qz *= qn;
    float rb[9];
    rb[0] = 1.f - 2.f*(qy*qy + qz*qz); rb[1] = 2.f*(qx*qy - qw*qz); rb[2] = 2.f*(qx*qz + qw*qy);
    rb[3] = 2.f*(qx*qy + qw*qz); rb[4] = 1.f - 2.f*(qx*qx + qz*qz); rb[5] = 2.f*(qy*qz - qw*qx);
    rb[6] = 2.f*(qx*qz - qw*qy); rb[7] = 2.f*(qy*qz + qw*qx); rb[8] = 1.f - 2.f*(qx*qx + qy*qy);

    float fr[8][9], ft[8][3];
    const float* ang = angles + (size_t)p * 14;
#pragma unroll
    for (int g = 0; g < 8; g++) {
        const float* df = &sdf[(s*8 + g)*16];
        float c, sn;
        if (g == 0) { c = 1.f; sn = 0.f; }
        else { sn = ang[(g-1)*2 + 0]; c = ang[(g-1)*2 + 1]; }
#pragma unroll
        for (int i = 0; i < 3; i++) {
            float d0 = df[i*4+0], d1 = df[i*4+1], d2 = df[i*4+2];
            fr[g][i*3+0] = d0;
            fr[g][i*3+1] = d1*c + d2*sn;
            fr[g][i*3+2] = d2*c - d1*sn;
            ft[g][i] = df[i*4+3];
        }
    }
#pragma unroll
    for (int g = 5; g <= 7; g++) {
        float r[9], t[3];
        const float* r1 = fr[g-1];
        const float* t1 = ft[g-1];
#pragma unroll
        for (int i = 0; i < 3; i++) {
#pragma unroll
            for (int j = 0; j < 3; j++)
                r[i*3+j] = r1[i*3+0]*fr[g][0*3+j] + r1[i*3+1]*fr[g][1*3+j] + r1[i*3+2]*fr[g][2*3+j];
            t[i] = r1[i*3+0]*ft[g][0] + r1[i*3+1]*ft[g][1] + r1[i*3+2]*ft[g][2] + t1[i];
        }
#pragma unroll
        for (int i = 0; i < 9; i++) fr[g][i] = r[i];
#pragma unroll
        for (int i = 0; i < 3; i++) ft[g][i] = t[i];
    }
#pragma unroll
    for (int g = 0; g < 8; g++) {
        float r[9], t[3];
#pragma unroll
        for (int i = 0; i < 3; i++) {
#pragma unroll
            for (int j = 0; j < 3; j++)
                r[i*3+j] = rb[i*3+0]*fr[g][0*3+j] + rb[i*3+1]*fr[g][1*3+j] + rb[i*3+2]*fr[g][2*3+j];
            t[i] = rb[i*3+0]*ft[g][0] + rb[i*3+1]*ft[g][1] + rb[i*3+2]*ft[g][2];
        }
#pragma unroll
        for (int i = 0; i < 9; i++) fr[g][i] = r[i];
        ft[g][0]=t[0]+tbx; ft[g][1]=t[1]+tby; ft[g][2]=t[2]+tbz;
    }
#pragma unroll
    for (int g = 0; g < 8; g++) {
#pragma unroll
        for (int a = 0; a < 14; a++) {
            if (sgi[s*14 + a] == g) {
                float m  = sm14[s*14 + a];
                float lx = slit[(s*14 + a)*3 + 0];
                float ly = slit[(s*14 + a)*3 + 1];
                float lz = slit[(s*14 + a)*3 + 2];
                float px = (fr[g][0]*lx + fr[g][1]*ly + fr[g][2]*lz + ft[g][0]) * m;
                float py = (fr[g][3]*lx + fr[g][4]*ly + fr[g][5]*lz + ft[g][1]) * m;
                float pz = (fr[g][6]*lx + fr[g][7]*ly + fr[g][8]*lz + ft[g][2]) * m;
                predL[threadIdx.x][a*3+0] = px;
                predL[threadIdx.x][a*3+1] = py;
                predL[threadIdx.x][a*3+2] = pz;
                out_pred[((size_t)p*14 + a)*3 + 0] = px;
                out_pred[((size_t)p*14 + a)*3 + 1] = py;
                out_pred[((size_t)p*14 + a)*3 + 2] = pz;
            }
        }
    }
#pragma unroll
    for (int a = 0; a < 14; a++) out_m14[(size_t)p*14 + a] = sm14[s*14 + a];

    const int* idx = residx + (size_t)p * 37;
#pragma unroll
    for (int a = 0; a < 37; a++) {
        int id = idx[a];
        out_final[((size_t)p*37 + a)*3 + 0] = predL[threadIdx.x][id*3+0];
        out_final[((size_t)p*37 + a)*3 + 1] = predL[threadIdx.x][id*3+1];
        out_final[((size_t)p*37 + a)*3 + 2] = predL[threadIdx.x][id*3+2];
        out_m37[(size_t)p*37 + a] = sm37[s*37 + a];
    }
}

extern "C" void kernel_launch(void* const* d_in, const int* in_sizes, int n_in,
                              void* d_out, int out_size, void* d_ws, size_t ws_size,
                              hipStream_t stream) {
    const float* act        = (const float*)d_in[0];
    const float* angles     = (const float*)d_in[1];
    const float* rigids     = (const float*)d_in[2];
    const int*   fixed_mask = (const int*)d_in[3];
    const int*   seq_t      = (const int*)d_in[4];
    const int*   residx     = (const int*)d_in[5];
    const float* lng        = (const float*)d_in[6];
    const float* lnb        = (const float*)d_in[7];
    const float* w1         = (const float*)d_in[8];
    const float* b1         = (const float*)d_in[9];
    const float* w2         = (const float*)d_in[10];
    const float* b2         = (const float*)d_in[11];
    const float* w3         = (const float*)d_in[12];
    const float* b3         = (const float*)d_in[13];
    const float* dfr        = (const float*)d_in[14];
    const int*   gidx       = (const int*)d_in[15];
    const float* a14m       = (const float*)d_in[16];
    const float* a37m       = (const float*)d_in[17];
    const float* litp       = (const float*)d_in[18];

    float* out        = (float*)d_out;
    float* out_logits = out;
    float* out_seq    = out_logits + (size_t)M_TOTAL * NRES;
    float* out_pred   = out_seq    + (size_t)M_TOTAL;
    float* out_final  = out_pred   + (size_t)M_TOTAL * 42;
    float* out_m14    = out_final  + (size_t)M_TOTAL * 111;
    float* out_m37    = out_m14    + (size_t)M_TOTAL * 14;

    char* wsp = (char*)d_ws;
    int*   seq0i = (int*)wsp;   wsp += (size_t)M_TOTAL * sizeof(int);
    short* w1h   = (short*)wsp; wsp += (size_t)H_ * C_ * sizeof(short);
    short* w1l   = (short*)wsp; wsp += (size_t)H_ * C_ * sizeof(short);
    short* w2h   = (short*)wsp; wsp += (size_t)H_ * H_ * sizeof(short);
    short* w2l   = (short*)wsp; wsp += (size_t)H_ * H_ * sizeof(short);
    short* w3h   = (short*)wsp; wsp += (size_t)128 * H_ * sizeof(short);
    short* w3l   = (short*)wsp; wsp += (size_t)128 * H_ * sizeof(short);
    short* Xh    = (short*)wsp; wsp += (size_t)M_TOTAL * C_ * sizeof(short);
    short* Xl    = (short*)wsp; wsp += (size_t)M_TOTAL * C_ * sizeof(short);

    size_t fixed_bytes = (size_t)(wsp - (char*)d_ws);
    size_t per_row = 4ull * H_ * sizeof(short);   // H1h/H1l/H2h/H2l
    size_t avail = ws_size - fixed_bytes;
    int chunkM = 4096;
    if (avail >= (size_t)M_TOTAL * per_row)      chunkM = M_TOTAL;
    else if (avail >= 16384ull * per_row)        chunkM = 16384;
    else if (avail >= 8192ull * per_row)         chunkM = 8192;

    short* H1h = (short*)wsp; wsp += (size_t)chunkM * H_ * sizeof(short);
    short* H1l = (short*)wsp; wsp += (size_t)chunkM * H_ * sizeof(short);
    short* H2h = (short*)wsp; wsp += (size_t)chunkM * H_ * sizeof(short);
    short* H2l = (short*)wsp;

    conv_w_kernel<<<dim3(H_/32, C_/32), 256, 0, stream>>>(w1, w1h, w1l, C_, H_, H_);
    conv_w_kernel<<<dim3(H_/32, H_/32), 256, 0, stream>>>(w2, w2h, w2l, H_, H_, H_);
    conv_w_kernel<<<dim3(128/32, H_/32), 256, 0, stream>>>(w3, w3h, w3l, H_, NRES, 128);

    ln_split_kernel<<<M_TOTAL/4, 256, 0, stream>>>(act, lng, lnb, Xh, Xl);

    for (int c = 0; c < M_TOTAL / chunkM; c++) {
        int m0 = c * chunkM;
        // GEMM1: LN'd act planes @ w1 (K=384)
        presplit_gemm256<<<dim3(chunkM/256, H_/256), 512, 0, stream>>>(
            Xh + (size_t)m0 * C_, Xl + (size_t)m0 * C_, w1h, w1l, b1, H1h, H1l, C_, H_);
        // GEMM2: H1 @ w2 (K=1024)
        presplit_gemm256<<<dim3(chunkM/256, H_/256), 512, 0, stream>>>(
            H1h, H1l, w2h, w2l, b2, H2h, H2l, H_, H_);
        // GEMM3 + logits + argmax + mask, fused (64-row blocks)
        gemm3_fused<<<chunkM/64, 256, 0, stream>>>(H2h, H2l, w3h, w3l, b3,
                                                   fixed_mask, seq_t,
                                                   out_logits, out_seq, seq0i, m0);
    }

    geom_kernel<<<M_TOTAL/128, 128, 0, stream>>>(angles, rigids, seq0i, residx,
                                                 dfr, gidx, a14m, a37m, litp,
                                                 out_pred, out_final, out_m14, out_m37);
}

// Round 7
// 467.943 us; speedup vs baseline: 1.2010x; 1.0002x over previous
//
#include <hip/hip_runtime.h>
#include <math.h>

#define B_ 32
#define N_ 1024
#define C_ 384
#define H_ 1024
#define NRES 20
#define NTAB 21
#define M_TOTAL (B_*N_)   // 32768
#define BK 32

typedef __attribute__((ext_vector_type(8))) short bf16x8;
typedef __attribute__((ext_vector_type(4))) float f32x4;

#define GLOAD_LDS(gptr, lptr) \
    __builtin_amdgcn_global_load_lds( \
        (const __attribute__((address_space(1))) void*)(gptr), \
        (__attribute__((address_space(3))) void*)(lptr), 16, 0, 0)

__device__ inline short bf16_rne(float v) {
    unsigned u = __float_as_uint(v);
    unsigned r = u + 0x7fffu + ((u >> 16) & 1u);
    return (short)(r >> 16);
}
// v ~= hi + lo, each bf16 (RNE). ~16 mantissa bits captured.
__device__ inline void split2(float v, short& h, short& l) {
    unsigned u = __float_as_uint(v);
    unsigned r = (u + 0x7fffu + ((u >> 16) & 1u)) & 0xffff0000u;
    h = (short)(r >> 16);
    l = bf16_rne(v - __uint_as_float(r));
}

// ---------------- LN + split: one wave per row, full M ----------------
__global__ __launch_bounds__(256) void ln_split_kernel(const float* __restrict__ act,
                                                       const float* __restrict__ lng,
                                                       const float* __restrict__ lnb,
                                                       short* __restrict__ Xh,
                                                       short* __restrict__ Xl) {
    int wave = threadIdx.x >> 6;
    int lane = threadIdx.x & 63;
    int row  = blockIdx.x * 4 + wave;
    const float* x = act + (size_t)row * C_;
    float v[6];
    float s = 0.f;
#pragma unroll
    for (int i = 0; i < 6; i++) { v[i] = x[lane + i*64]; s += v[i]; }
#pragma unroll
    for (int off = 32; off > 0; off >>= 1) s += __shfl_xor(s, off, 64);
    float mu = s * (1.0f/384.0f);
    float vs = 0.f;
#pragma unroll
    for (int i = 0; i < 6; i++) { float d = v[i]-mu; vs += d*d; }
#pragma unroll
    for (int off = 32; off > 0; off >>= 1) vs += __shfl_xor(vs, off, 64);
    float rstd = 1.0f / sqrtf(vs * (1.0f/384.0f) + 1e-5f);
#pragma unroll
    for (int i = 0; i < 6; i++) {
        int col = lane + i*64;
        float y = (v[i] - mu) * rstd * lng[col] + lnb[col];
        short h, l; split2(y, h, l);
        Xh[(size_t)row * C_ + col] = h;
        Xl[(size_t)row * C_ + col] = l;
    }
}

// ---------------- weight transpose + split-bf16 convert ----------------
__global__ __launch_bounds__(256) void conv_w_kernel(const float* __restrict__ w,
                                                     short* __restrict__ th,
                                                     short* __restrict__ tl,
                                                     int K, int N, int Npad) {
    __shared__ float t[32][33];
    int n0 = blockIdx.x * 32, k0 = blockIdx.y * 32;
    int tx = threadIdx.x & 31, ty = threadIdx.x >> 5;
#pragma unroll
    for (int i = ty; i < 32; i += 8) {
        int k = k0 + i, n = n0 + tx;
        t[i][tx] = (n < N) ? w[(size_t)k * N + n] : 0.f;
    }
    __syncthreads();
#pragma unroll
    for (int i = ty; i < 32; i += 8) {
        int n = n0 + i, k = k0 + tx;
        short h, l; split2(t[tx][i], h, l);
        th[(size_t)n * K + k] = h;
        tl[(size_t)n * K + k] = l;
    }
}

// ---------------- presplit GEMM: 256x256 tile, 8 waves, 4-phase counted-vmcnt ----
// R2 schedule (plain blockIdx mapping: default round-robin already co-locates
// same-A-panel blocks on one XCD since gridDim.x % 8 == 0; R6's swizzle broke
// that, FETCH 49->135 MB).
// FUSE=true (GEMM2): instead of storing H2 to global, round-trip the relu'd
// split tile through LDS (2 x 128-row passes) and MFMA it against w3 directly,
// atomically accumulating logits partials. H2 never materializes in HBM.
// Numerics identical to the old gemm3 path: logits computed from the same
// split2-quantized hi/lo planes with the same triple-MFMA; only the 4-way
// (n-panel) summation order changes (atomics), ~1ulp.
// grid: (chunkM/256, H/256), 512 threads.
template<bool FUSE>
__global__ __launch_bounds__(512, 2) void presplit_gemm256(
    const short* __restrict__ Ahg, const short* __restrict__ Alg,
    const short* __restrict__ BTh, const short* __restrict__ BTl,
    const float* __restrict__ bias,
    short* __restrict__ Ch, short* __restrict__ Cl,
    int K, int ldc,
    const short* __restrict__ W3h, const short* __restrict__ W3l,
    float* __restrict__ logit_acc, int m0c)
{
    __shared__ short P[4][2][256][32];   // planes {Ah,Al,Bh,Bl} x dbuf, 128 KiB
    const int BUFS = 256*32;             // shorts per buffer within a plane
    int tid = threadIdx.x;
    int m0 = blockIdx.x * 256;
    int n0 = blockIdx.y * 256;
    int lane = tid & 63, wv = tid >> 6;
    int wr = wv >> 2, wc = wv & 3;       // wave grid 2M x 4N -> wave tile 128x64
    int fm = lane & 15, kg = lane >> 4;

    // staging role: wave wv stages plane (wv>>1), row-half (wv&1): 8 DMAs/step
    int pl = wv >> 1, hf = wv & 1;
    const short* gsrc = (pl == 0) ? Ahg : (pl == 1) ? Alg : (pl == 2) ? BTh : BTl;
    int base = (pl < 2) ? m0 : n0;
    // lane l -> LDS slot (row16=l>>2, cb=l&3); fetch global cb ^ swz(row16)
    int swcb = (lane & 3) ^ ((lane >> 3) & 3);
    const short* gp = gsrc + (size_t)(base + hf*128 + (lane >> 2)) * K + swcb * 8;
    short* lpl = &P[pl][0][0][0] + hf * (128*32);

    // swizzled read col-offset (shorts); identical for all frag rows since
    // (row>>1)&3 == (fm>>1)&3 for row = 16*q + fm.
    int sz = (kg ^ ((fm >> 1) & 3)) * 8;
    const short* raH = &P[0][0][wr*128 + fm][0] + sz;
    const short* raL = &P[1][0][wr*128 + fm][0] + sz;
    const short* rbH = &P[2][0][wc*64  + fm][0] + sz;
    const short* rbL = &P[3][0][wc*64  + fm][0] + sz;

#define STAGE(c, bsel, koff) \
    GLOAD_LDS(gp + (size_t)((c)*16) * K + (koff), lpl + (bsel)*BUFS + (c)*512)

#define TRIPLE(ai, aj, AH, AL, BH, BL) { \
    f32x4 cc = acc[ai][aj]; \
    cc = __builtin_amdgcn_mfma_f32_16x16x32_bf16(AL, BH, cc, 0, 0, 0); \
    cc = __builtin_amdgcn_mfma_f32_16x16x32_bf16(AH, BL, cc, 0, 0, 0); \
    cc = __builtin_amdgcn_mfma_f32_16x16x32_bf16(AH, BH, cc, 0, 0, 0); \
    acc[ai][aj] = cc; }

    f32x4 acc[8][4] = {};
    const int NT = K / BK;

    // prologue: stage tile 0 into buffer 0
#pragma unroll
    for (int c = 0; c < 8; c++) STAGE(c, 0, 0);

    for (int t = 0; t < NT; ++t) {
        int cur = t & 1, nxt = cur ^ 1;
        size_t koff = (size_t)(t + 1) * BK;
        bool pf = (t + 1 < NT);

        bf16x8 a_h[4], a_l[4], b_h[4], b_l[4];

        // ---- phase 0: a0-3 + b0-1, MFMA i0-3 x j0-1 ----
        if (pf) {
            STAGE(0, nxt, koff); STAGE(1, nxt, koff);
            asm volatile("s_waitcnt vmcnt(2)" ::: "memory");
        } else {
            asm volatile("s_waitcnt vmcnt(0)" ::: "memory");
        }
        __builtin_amdgcn_s_barrier();
        __builtin_amdgcn_sched_barrier(0);
#pragma unroll
        for (int i = 0; i < 4; i++) {
            a_h[i] = *(const bf16x8*)(raH + cur*BUFS + i*512);
            a_l[i] = *(const bf16x8*)(raL + cur*BUFS + i*512);
        }
#pragma unroll
        for (int j = 0; j < 2; j++) {
            b_h[j] = *(const bf16x8*)(rbH + cur*BUFS + j*512);
            b_l[j] = *(const bf16x8*)(rbL + cur*BUFS + j*512);
        }
        __builtin_amdgcn_s_setprio(1);
#pragma unroll
        for (int i = 0; i < 4; i++)
#pragma unroll
            for (int j = 0; j < 2; j++) TRIPLE(i, j, a_h[i], a_l[i], b_h[j], b_l[j]);
        __builtin_amdgcn_s_setprio(0);
        __builtin_amdgcn_s_barrier();

        // ---- phase 1: b2-3, MFMA i0-3 x j2-3 ----
        if (pf) { STAGE(2, nxt, koff); STAGE(3, nxt, koff); }
#pragma unroll
        for (int j = 0; j < 2; j++) {
            b_h[2+j] = *(const bf16x8*)(rbH + cur*BUFS + (2+j)*512);
            b_l[2+j] = *(const bf16x8*)(rbL + cur*BUFS + (2+j)*512);
        }
        __builtin_amdgcn_s_barrier();
        __builtin_amdgcn_s_setprio(1);
#pragma unroll
        for (int i = 0; i < 4; i++)
#pragma unroll
            for (int j = 0; j < 2; j++) TRIPLE(i, 2+j, a_h[i], a_l[i], b_h[2+j], b_l[2+j]);
        __builtin_amdgcn_s_setprio(0);
        __builtin_amdgcn_s_barrier();

        // ---- phase 2: a4-7, MFMA i4-7 x j0-1 ----
        if (pf) { STAGE(4, nxt, koff); STAGE(5, nxt, koff); }
#pragma unroll
        for (int i = 0; i < 4; i++) {
            a_h[i] = *(const bf16x8*)(raH + cur*BUFS + (4+i)*512);
            a_l[i] = *(const bf16x8*)(raL + cur*BUFS + (4+i)*512);
        }
        __builtin_amdgcn_s_barrier();
        __builtin_amdgcn_s_setprio(1);
#pragma unroll
        for (int i = 0; i < 4; i++)
#pragma unroll
            for (int j = 0; j < 2; j++) TRIPLE(4+i, j, a_h[i], a_l[i], b_h[j], b_l[j]);
        __builtin_amdgcn_s_setprio(0);
        __builtin_amdgcn_s_barrier();

        // ---- phase 3: MFMA i4-7 x j2-3 ----
        if (pf) { STAGE(6, nxt, koff); STAGE(7, nxt, koff); }
        __builtin_amdgcn_s_barrier();
        __builtin_amdgcn_s_setprio(1);
#pragma unroll
        for (int i = 0; i < 4; i++)
#pragma unroll
            for (int j = 0; j < 2; j++) TRIPLE(4+i, 2+j, a_h[i], a_l[i], b_h[2+j], b_l[2+j]);
        __builtin_amdgcn_s_setprio(0);
        __builtin_amdgcn_s_barrier();
    }

    if (!FUSE) {
        // store epilogue: relu + split2 -> Ch/Cl planes
#pragma unroll
        for (int i = 0; i < 8; i++)
#pragma unroll
            for (int j = 0; j < 4; j++) {
                int col = n0 + wc*64 + j*16 + fm;
                float bs = bias[col];
#pragma unroll
                for (int r2 = 0; r2 < 4; r2++) {
                    int row = m0 + wr*128 + i*16 + kg*4 + r2;
                    float v = fmaxf(acc[i][j][r2] + bs, 0.f);
                    short h, l; split2(v, h, l);
                    Ch[(size_t)row * ldc + col] = h;
                    Cl[(size_t)row * ldc + col] = l;
                }
            }
    } else {
        // fused logits epilogue: two 128-row passes through LDS.
        // LDS layout: u32[128][256], word = (hi<<16)|lo of split2(relu(acc+b)).
        // col swizzled by ((localrow&15)<<1) to break the 1KB row stride.
        unsigned* L32 = (unsigned*)&P[0][0][0][0];
#pragma unroll
        for (int h = 0; h < 2; h++) {
            if (wr == h) {
#pragma unroll
                for (int i = 0; i < 8; i++)
#pragma unroll
                    for (int j = 0; j < 4; j++) {
                        int col = wc*64 + j*16 + fm;
                        float bs = bias[n0 + col];
#pragma unroll
                        for (int r2 = 0; r2 < 4; r2++) {
                            int lr = i*16 + kg*4 + r2;
                            float v = fmaxf(acc[i][j][r2] + bs, 0.f);
                            short sh, sl; split2(v, sh, sl);
                            L32[lr*256 + (col ^ ((lr & 15) << 1))] =
                                ((unsigned)(unsigned short)sh << 16) | (unsigned short)sl;
                        }
                    }
            }
            __syncthreads();
            // each wave: 16 rows (wv*16..+15) x k=256 local cols vs w3 slice.
            // A-frag: lane row = wv*16+fm, k = s*32 + kg*8 + c (standard layout).
            // B-frag: w3T[c][k] global (L2-hot, rows >=20 are zeros).
            f32x4 pl0 = {}, pl1 = {};
            int rbase = (wv*16 + fm) * 256;
            int swr = fm << 1;
#pragma unroll
            for (int s = 0; s < 8; s++) {
                int kb = s*32 + kg*8;
                bf16x8 A_h, A_l;
#pragma unroll
                for (int c = 0; c < 8; c++) {
                    unsigned u = L32[rbase + ((kb + c) ^ swr)];
                    A_h[c] = (short)(u >> 16);
                    A_l[c] = (short)(u & 0xffffu);
                }
                size_t wk = (size_t)(n0 + kb);
                bf16x8 B0h = *(const bf16x8*)&W3h[(size_t)fm * H_ + wk];
                bf16x8 B0l = *(const bf16x8*)&W3l[(size_t)fm * H_ + wk];
                bf16x8 B1h = *(const bf16x8*)&W3h[(size_t)(16 + fm) * H_ + wk];
                bf16x8 B1l = *(const bf16x8*)&W3l[(size_t)(16 + fm) * H_ + wk];
                pl0 = __builtin_amdgcn_mfma_f32_16x16x32_bf16(A_l, B0h, pl0, 0, 0, 0);
                pl0 = __builtin_amdgcn_mfma_f32_16x16x32_bf16(A_h, B0l, pl0, 0, 0, 0);
                pl0 = __builtin_amdgcn_mfma_f32_16x16x32_bf16(A_h, B0h, pl0, 0, 0, 0);
                pl1 = __builtin_amdgcn_mfma_f32_16x16x32_bf16(A_l, B1h, pl1, 0, 0, 0);
                pl1 = __builtin_amdgcn_mfma_f32_16x16x32_bf16(A_h, B1l, pl1, 0, 0, 0);
                pl1 = __builtin_amdgcn_mfma_f32_16x16x32_bf16(A_h, B1h, pl1, 0, 0, 0);
            }
            // C-layout: col = fm (+16 for pl1), row = kg*4 + r
            int growb = m0c + m0 + h*128 + wv*16 + kg*4;
#pragma unroll
            for (int r2 = 0; r2 < 4; r2++)
                atomicAdd(&logit_acc[(size_t)(growb + r2) * NRES + fm], pl0[r2]);
            if (fm < 4) {
#pragma unroll
                for (int r2 = 0; r2 < 4; r2++)
                    atomicAdd(&logit_acc[(size_t)(growb + r2) * NRES + 16 + fm], pl1[r2]);
            }
            __syncthreads();
        }
    }
#undef STAGE
#undef TRIPLE
}

// ---------------- argmax: bias + argmax + mask over atomically-summed logits ----
__global__ __launch_bounds__(256) void argmax_kernel(
    float* __restrict__ logits, const float* __restrict__ b3,
    const int* __restrict__ fixed_mask, const int* __restrict__ seq_t,
    float* __restrict__ seq_out, int* __restrict__ seq_int, int m0c)
{
    int grow = m0c + blockIdx.x * 256 + threadIdx.x;
    float* lg = logits + (size_t)grow * NRES;
    float best = -1e30f; int bi = 0;
#pragma unroll
    for (int n = 0; n < NRES; n++) {
        float s = lg[n] + b3[n];
        lg[n] = s;
        if (s > best) { best = s; bi = n; }
    }
    int fmk = fixed_mask[grow];
    int sv = fmk ? seq_t[grow] : bi;
    seq_int[grow] = sv;
    seq_out[grow] = (float)sv;
}

// ---------------- geometry: one thread per (b,n) ----------------
__global__ __launch_bounds__(128) void geom_kernel(
    const float* __restrict__ angles, const float* __restrict__ rigids,
    const int* __restrict__ seq0i, const int* __restrict__ residx,
    const float* __restrict__ dframes, const int* __restrict__ gidx,
    const float* __restrict__ a14m, const float* __restrict__ a37m,
    const float* __restrict__ litp,
    float* __restrict__ out_pred, float* __restrict__ out_final,
    float* __restrict__ out_m14, float* __restrict__ out_m37)
{
    __shared__ float sdf[NTAB*8*16];
    __shared__ int   sgi[NTAB*14];
    __shared__ float sm14[NTAB*14];
    __shared__ float sm37[NTAB*37];
    __shared__ float slit[NTAB*14*3];
    __shared__ float predL[128][43];

    for (int i = threadIdx.x; i < NTAB*128; i += 128) sdf[i] = dframes[i];
    for (int i = threadIdx.x; i < NTAB*14; i += 128) { sgi[i] = gidx[i]; sm14[i] = a14m[i]; }
    for (int i = threadIdx.x; i < NTAB*37; i += 128) sm37[i] = a37m[i];
    for (int i = threadIdx.x; i < NTAB*42; i += 128) slit[i] = litp[i];
    __syncthreads();

    int p = blockIdx.x * 128 + threadIdx.x;
    int s = seq0i[p];

    const float* rg = rigids + (size_t)p * 7;
    float qw = rg[0], qx = rg[1], qy = rg[2], qz = rg[3];
    float tbx = rg[4], tby = rg[5], tbz = rg[6];
    float qn = 1.0f / sqrtf(qw*qw + qx*qx + qy*qy + qz*qz + 1e-8f);
    qw *= qn; qx *= qn; qy *= qn; qz *= qn;
    float rb[9];
    rb[0] = 1.f - 2.f*(qy*qy + qz*qz); rb[1] = 2.f*(qx*qy - qw*qz); rb[2] = 2.f*(qx*qz + qw*qy);
    rb[3] = 2.f*(qx*qy + qw*qz); rb[4] = 1.f - 2.f*(qx*qx + qz*qz); rb[5] = 2.f*(qy*qz - qw*qx);
    rb[6] = 2.f*(qx*qz - qw*qy); rb[7] = 2.f*(qy*qz + qw*qx); rb[8] = 1.f - 2.f*(qx*qx + qy*qy);

    float fr[8][9], ft[8][3];
    const float* ang = angles + (size_t)p * 14;
#pragma unroll
    for (int g = 0; g < 8; g++) {
        const float* df = &sdf[(s*8 + g)*16];
        float c, sn;
        if (g == 0) { c = 1.f; sn = 0.f; }
        else { sn = ang[(g-1)*2 + 0]; c = ang[(g-1)*2 + 1]; }
#pragma unroll
        for (int i = 0; i < 3; i++) {
            float d0 = df[i*4+0], d1 = df[i*4+1], d2 = df[i*4+2];
            fr[g][i*3+0] = d0;
            fr[g][i*3+1] = d1*c + d2*sn;
            fr[g][i*3+2] = d2*c - d1*sn;
            ft[g][i] = df[i*4+3];
        }
    }
#pragma unroll
    for (int g = 5; g <= 7; g++) {
        float r[9], t[3];
        const float* r1 = fr[g-1];
        const float* t1 = ft[g-1];
#pragma unroll
        for (int i = 0; i < 3; i++) {
#pragma unroll
            for (int j = 0; j < 3; j++)
                r[i*3+j] = r1[i*3+0]*fr[g][0*3+j] + r1[i*3+1]*fr[g][1*3+j] + r1[i*3+2]*fr[g][2*3+j];
            t[i] = r1[i*3+0]*ft[g][0] + r1[i*3+1]*ft[g][1] + r1[i*3+2]*ft[g][2] + t1[i];
        }
#pragma unroll
        for (int i = 0; i < 9; i++) fr[g][i] = r[i];
#pragma unroll
        for (int i = 0; i < 3; i++) ft[g][i] = t[i];
    }
#pragma unroll
    for (int g = 0; g < 8; g++) {
        float r[9], t[3];
#pragma unroll
        for (int i = 0; i < 3; i++) {
#pragma unroll
            for (int j = 0; j < 3; j++)
                r[i*3+j] = rb[i*3+0]*fr[g][0*3+j] + rb[i*3+1]*fr[g][1*3+j] + rb[i*3+2]*fr[g][2*3+j];
            t[i] = rb[i*3+0]*ft[g][0] + rb[i*3+1]*ft[g][1] + rb[i*3+2]*ft[g][2];
        }
#pragma unroll
        for (int i = 0; i < 9; i++) fr[g][i] = r[i];
        ft[g][0]=t[0]+tbx; ft[g][1]=t[1]+tby; ft[g][2]=t[2]+tbz;
    }
#pragma unroll
    for (int g = 0; g < 8; g++) {
#pragma unroll
        for (int a = 0; a < 14; a++) {
            if (sgi[s*14 + a] == g) {
                float m  = sm14[s*14 + a];
                float lx = slit[(s*14 + a)*3 + 0];
                float ly = slit[(s*14 + a)*3 + 1];
                float lz = slit[(s*14 + a)*3 + 2];
                float px = (fr[g][0]*lx + fr[g][1]*ly + fr[g][2]*lz + ft[g][0]) * m;
                float py = (fr[g][3]*lx + fr[g][4]*ly + fr[g][5]*lz + ft[g][1]) * m;
                float pz = (fr[g][6]*lx + fr[g][7]*ly + fr[g][8]*lz + ft[g][2]) * m;
                predL[threadIdx.x][a*3+0] = px;
                predL[threadIdx.x][a*3+1] = py;
                predL[threadIdx.x][a*3+2] = pz;
                out_pred[((size_t)p*14 + a)*3 + 0] = px;
                out_pred[((size_t)p*14 + a)*3 + 1] = py;
                out_pred[((size_t)p*14 + a)*3 + 2] = pz;
            }
        }
    }
#pragma unroll
    for (int a = 0; a < 14; a++) out_m14[(size_t)p*14 + a] = sm14[s*14 + a];

    const int* idx = residx + (size_t)p * 37;
#pragma unroll
    for (int a = 0; a < 37; a++) {
        int id = idx[a];
        out_final[((size_t)p*37 + a)*3 + 0] = predL[threadIdx.x][id*3+0];
        out_final[((size_t)p*37 + a)*3 + 1] = predL[threadIdx.x][id*3+1];
        out_final[((size_t)p*37 + a)*3 + 2] = predL[threadIdx.x][id*3+2];
        out_m37[(size_t)p*37 + a] = sm37[s*37 + a];
    }
}

extern "C" void kernel_launch(void* const* d_in, const int* in_sizes, int n_in,
                              void* d_out, int out_size, void* d_ws, size_t ws_size,
                              hipStream_t stream) {
    const float* act        = (const float*)d_in[0];
    const float* angles     = (const float*)d_in[1];
    const float* rigids     = (const float*)d_in[2];
    const int*   fixed_mask = (const int*)d_in[3];
    const int*   seq_t      = (const int*)d_in[4];
    const int*   residx     = (const int*)d_in[5];
    const float* lng        = (const float*)d_in[6];
    const float* lnb        = (const float*)d_in[7];
    const float* w1         = (const float*)d_in[8];
    const float* b1         = (const float*)d_in[9];
    const float* w2         = (const float*)d_in[10];
    const float* b2         = (const float*)d_in[11];
    const float* w3         = (const float*)d_in[12];
    const float* b3         = (const float*)d_in[13];
    const float* dfr        = (const float*)d_in[14];
    const int*   gidx       = (const int*)d_in[15];
    const float* a14m       = (const float*)d_in[16];
    const float* a37m       = (const float*)d_in[17];
    const float* litp       = (const float*)d_in[18];

    float* out        = (float*)d_out;
    float* out_logits = out;
    float* out_seq    = out_logits + (size_t)M_TOTAL * NRES;
    float* out_pred   = out_seq    + (size_t)M_TOTAL;
    float* out_final  = out_pred   + (size_t)M_TOTAL * 42;
    float* out_m14    = out_final  + (size_t)M_TOTAL * 111;
    float* out_m37    = out_m14    + (size_t)M_TOTAL * 14;

    char* wsp = (char*)d_ws;
    int*   seq0i = (int*)wsp;   wsp += (size_t)M_TOTAL * sizeof(int);
    short* w1h   = (short*)wsp; wsp += (size_t)H_ * C_ * sizeof(short);
    short* w1l   = (short*)wsp; wsp += (size_t)H_ * C_ * sizeof(short);
    short* w2h   = (short*)wsp; wsp += (size_t)H_ * H_ * sizeof(short);
    short* w2l   = (short*)wsp; wsp += (size_t)H_ * H_ * sizeof(short);
    short* w3h   = (short*)wsp; wsp += (size_t)128 * H_ * sizeof(short);
    short* w3l   = (short*)wsp; wsp += (size_t)128 * H_ * sizeof(short);
    short* Xh    = (short*)wsp; wsp += (size_t)M_TOTAL * C_ * sizeof(short);
    short* Xl    = (short*)wsp; wsp += (size_t)M_TOTAL * C_ * sizeof(short);

    size_t fixed_bytes = (size_t)(wsp - (char*)d_ws);
    size_t per_row = 2ull * H_ * sizeof(short);   // H1h/H1l only (H2 eliminated)
    size_t avail = ws_size - fixed_bytes;
    int chunkM = 4096;
    if (avail >= (size_t)M_TOTAL * per_row)      chunkM = M_TOTAL;
    else if (avail >= 16384ull * per_row)        chunkM = 16384;
    else if (avail >= 8192ull * per_row)         chunkM = 8192;

    short* H1h = (short*)wsp; wsp += (size_t)chunkM * H_ * sizeof(short);
    short* H1l = (short*)wsp;

    // logits accumulated via atomics into out_logits -> zero it first
    hipMemsetAsync(out_logits, 0, (size_t)M_TOTAL * NRES * sizeof(float), stream);

    conv_w_kernel<<<dim3(H_/32, C_/32), 256, 0, stream>>>(w1, w1h, w1l, C_, H_, H_);
    conv_w_kernel<<<dim3(H_/32, H_/32), 256, 0, stream>>>(w2, w2h, w2l, H_, H_, H_);
    conv_w_kernel<<<dim3(128/32, H_/32), 256, 0, stream>>>(w3, w3h, w3l, H_, NRES, 128);

    ln_split_kernel<<<M_TOTAL/4, 256, 0, stream>>>(act, lng, lnb, Xh, Xl);

    for (int c = 0; c < M_TOTAL / chunkM; c++) {
        int m0 = c * chunkM;
        // GEMM1: LN'd act planes @ w1 (K=384) -> H1 planes
        presplit_gemm256<false><<<dim3(chunkM/256, H_/256), 512, 0, stream>>>(
            Xh + (size_t)m0 * C_, Xl + (size_t)m0 * C_, w1h, w1l, b1,
            H1h, H1l, C_, H_, nullptr, nullptr, nullptr, 0);
        // GEMM2: H1 @ w2 (K=1024), fused logits epilogue (H2 never stored)
        presplit_gemm256<true><<<dim3(chunkM/256, H_/256), 512, 0, stream>>>(
            H1h, H1l, w2h, w2l, b2,
            nullptr, nullptr, H_, 0, w3h, w3l, out_logits, m0);
        // bias + argmax + mask
        argmax_kernel<<<chunkM/256, 256, 0, stream>>>(
            out_logits, b3, fixed_mask, seq_t, out_seq, seq0i, m0);
    }

    geom_kernel<<<M_TOTAL/128, 128, 0, stream>>>(angles, rigids, seq0i, residx,
                                                 dfr, gidx, a14m, a37m, litp,
                                                 out_pred, out_final, out_m14, out_m37);
}

// Round 8
// 460.076 us; speedup vs baseline: 1.2215x; 1.0171x over previous
//
#include <hip/hip_runtime.h>
#include <math.h>

#define B_ 32
#define N_ 1024
#define C_ 384
#define H_ 1024
#define NRES 20
#define NTAB 21
#define M_TOTAL (B_*N_)   // 32768
#define BK 32

typedef __attribute__((ext_vector_type(8))) short bf16x8;
typedef __attribute__((ext_vector_type(4))) float f32x4;

#define GLOAD_LDS(gptr, lptr) \
    __builtin_amdgcn_global_load_lds( \
        (const __attribute__((address_space(1))) void*)(gptr), \
        (__attribute__((address_space(3))) void*)(lptr), 16, 0, 0)

__device__ inline short bf16_rne(float v) {
    unsigned u = __float_as_uint(v);
    unsigned r = u + 0x7fffu + ((u >> 16) & 1u);
    return (short)(r >> 16);
}
// v ~= hi + lo, each bf16 (RNE). ~16 mantissa bits captured.
__device__ inline void split2(float v, short& h, short& l) {
    unsigned u = __float_as_uint(v);
    unsigned r = (u + 0x7fffu + ((u >> 16) & 1u)) & 0xffff0000u;
    h = (short)(r >> 16);
    l = bf16_rne(v - __uint_as_float(r));
}

// ---------------- LN + split: one wave per row, full M ----------------
__global__ __launch_bounds__(256) void ln_split_kernel(const float* __restrict__ act,
                                                       const float* __restrict__ lng,
                                                       const float* __restrict__ lnb,
                                                       short* __restrict__ Xh,
                                                       short* __restrict__ Xl) {
    int wave = threadIdx.x >> 6;
    int lane = threadIdx.x & 63;
    int row  = blockIdx.x * 4 + wave;
    const float* x = act + (size_t)row * C_;
    float v[6];
    float s = 0.f;
#pragma unroll
    for (int i = 0; i < 6; i++) { v[i] = x[lane + i*64]; s += v[i]; }
#pragma unroll
    for (int off = 32; off > 0; off >>= 1) s += __shfl_xor(s, off, 64);
    float mu = s * (1.0f/384.0f);
    float vs = 0.f;
#pragma unroll
    for (int i = 0; i < 6; i++) { float d = v[i]-mu; vs += d*d; }
#pragma unroll
    for (int off = 32; off > 0; off >>= 1) vs += __shfl_xor(vs, off, 64);
    float rstd = 1.0f / sqrtf(vs * (1.0f/384.0f) + 1e-5f);
#pragma unroll
    for (int i = 0; i < 6; i++) {
        int col = lane + i*64;
        float y = (v[i] - mu) * rstd * lng[col] + lnb[col];
        short h, l; split2(y, h, l);
        Xh[(size_t)row * C_ + col] = h;
        Xl[(size_t)row * C_ + col] = l;
    }
}

// ---------------- weight transpose + split-bf16 convert ----------------
__global__ __launch_bounds__(256) void conv_w_kernel(const float* __restrict__ w,
                                                     short* __restrict__ th,
                                                     short* __restrict__ tl,
                                                     int K, int N, int Npad) {
    __shared__ float t[32][33];
    int n0 = blockIdx.x * 32, k0 = blockIdx.y * 32;
    int tx = threadIdx.x & 31, ty = threadIdx.x >> 5;
#pragma unroll
    for (int i = ty; i < 32; i += 8) {
        int k = k0 + i, n = n0 + tx;
        t[i][tx] = (n < N) ? w[(size_t)k * N + n] : 0.f;
    }
    __syncthreads();
#pragma unroll
    for (int i = ty; i < 32; i += 8) {
        int n = n0 + i, k = k0 + tx;
        short h, l; split2(t[tx][i], h, l);
        th[(size_t)n * K + k] = h;
        tl[(size_t)n * K + k] = l;
    }
}

// ---------------- presplit GEMM: 256x256 tile, 8 waves, 4-phase counted-vmcnt ----
// R2 schedule, plain blockIdx mapping (default round-robin co-locates same-A
// blocks per XCD since gridDim.x % 8 == 0).
// FUSE=true (GEMM2): round-trip relu'd split tile through LDS, MFMA vs w3,
// atomically accumulate logits. H2 never hits HBM.
// grid: (chunkM/256, H/256), 512 threads.
template<bool FUSE>
__global__ __launch_bounds__(512, 2) void presplit_gemm256(
    const short* __restrict__ Ahg, const short* __restrict__ Alg,
    const short* __restrict__ BTh, const short* __restrict__ BTl,
    const float* __restrict__ bias,
    short* __restrict__ Ch, short* __restrict__ Cl,
    int K, int ldc,
    const short* __restrict__ W3h, const short* __restrict__ W3l,
    float* __restrict__ logit_acc, int m0c)
{
    __shared__ short P[4][2][256][32];   // planes {Ah,Al,Bh,Bl} x dbuf, 128 KiB
    const int BUFS = 256*32;             // shorts per buffer within a plane
    int tid = threadIdx.x;
    int m0 = blockIdx.x * 256;
    int n0 = blockIdx.y * 256;
    int lane = tid & 63, wv = tid >> 6;
    int wr = wv >> 2, wc = wv & 3;       // wave grid 2M x 4N -> wave tile 128x64
    int fm = lane & 15, kg = lane >> 4;

    // staging role: wave wv stages plane (wv>>1), row-half (wv&1): 8 DMAs/step
    int pl = wv >> 1, hf = wv & 1;
    const short* gsrc = (pl == 0) ? Ahg : (pl == 1) ? Alg : (pl == 2) ? BTh : BTl;
    int base = (pl < 2) ? m0 : n0;
    // lane l -> LDS slot (row16=l>>2, cb=l&3); fetch global cb ^ swz(row16)
    int swcb = (lane & 3) ^ ((lane >> 3) & 3);
    const short* gp = gsrc + (size_t)(base + hf*128 + (lane >> 2)) * K + swcb * 8;
    short* lpl = &P[pl][0][0][0] + hf * (128*32);

    // swizzled read col-offset (shorts); identical for all frag rows since
    // (row>>1)&3 == (fm>>1)&3 for row = 16*q + fm.
    int sz = (kg ^ ((fm >> 1) & 3)) * 8;
    const short* raH = &P[0][0][wr*128 + fm][0] + sz;
    const short* raL = &P[1][0][wr*128 + fm][0] + sz;
    const short* rbH = &P[2][0][wc*64  + fm][0] + sz;
    const short* rbL = &P[3][0][wc*64  + fm][0] + sz;

#define STAGE(c, bsel, koff) \
    GLOAD_LDS(gp + (size_t)((c)*16) * K + (koff), lpl + (bsel)*BUFS + (c)*512)

#define TRIPLE(ai, aj, AH, AL, BH, BL) { \
    f32x4 cc = acc[ai][aj]; \
    cc = __builtin_amdgcn_mfma_f32_16x16x32_bf16(AL, BH, cc, 0, 0, 0); \
    cc = __builtin_amdgcn_mfma_f32_16x16x32_bf16(AH, BL, cc, 0, 0, 0); \
    cc = __builtin_amdgcn_mfma_f32_16x16x32_bf16(AH, BH, cc, 0, 0, 0); \
    acc[ai][aj] = cc; }

    f32x4 acc[8][4] = {};
    const int NT = K / BK;

    // prologue: stage tile 0 into buffer 0
#pragma unroll
    for (int c = 0; c < 8; c++) STAGE(c, 0, 0);

    for (int t = 0; t < NT; ++t) {
        int cur = t & 1, nxt = cur ^ 1;
        size_t koff = (size_t)(t + 1) * BK;
        bool pf = (t + 1 < NT);

        bf16x8 a_h[4], a_l[4], b_h[4], b_l[4];

        // ---- phase 0: a0-3 + b0-1, MFMA i0-3 x j0-1 ----
        if (pf) {
            STAGE(0, nxt, koff); STAGE(1, nxt, koff);
            asm volatile("s_waitcnt vmcnt(2)" ::: "memory");
        } else {
            asm volatile("s_waitcnt vmcnt(0)" ::: "memory");
        }
        __builtin_amdgcn_s_barrier();
        __builtin_amdgcn_sched_barrier(0);
#pragma unroll
        for (int i = 0; i < 4; i++) {
            a_h[i] = *(const bf16x8*)(raH + cur*BUFS + i*512);
            a_l[i] = *(const bf16x8*)(raL + cur*BUFS + i*512);
        }
#pragma unroll
        for (int j = 0; j < 2; j++) {
            b_h[j] = *(const bf16x8*)(rbH + cur*BUFS + j*512);
            b_l[j] = *(const bf16x8*)(rbL + cur*BUFS + j*512);
        }
        __builtin_amdgcn_s_setprio(1);
#pragma unroll
        for (int i = 0; i < 4; i++)
#pragma unroll
            for (int j = 0; j < 2; j++) TRIPLE(i, j, a_h[i], a_l[i], b_h[j], b_l[j]);
        __builtin_amdgcn_s_setprio(0);
        __builtin_amdgcn_s_barrier();

        // ---- phase 1: b2-3, MFMA i0-3 x j2-3 ----
        if (pf) { STAGE(2, nxt, koff); STAGE(3, nxt, koff); }
#pragma unroll
        for (int j = 0; j < 2; j++) {
            b_h[2+j] = *(const bf16x8*)(rbH + cur*BUFS + (2+j)*512);
            b_l[2+j] = *(const bf16x8*)(rbL + cur*BUFS + (2+j)*512);
        }
        __builtin_amdgcn_s_barrier();
        __builtin_amdgcn_s_setprio(1);
#pragma unroll
        for (int i = 0; i < 4; i++)
#pragma unroll
            for (int j = 0; j < 2; j++) TRIPLE(i, 2+j, a_h[i], a_l[i], b_h[2+j], b_l[2+j]);
        __builtin_amdgcn_s_setprio(0);
        __builtin_amdgcn_s_barrier();

        // ---- phase 2: a4-7, MFMA i4-7 x j0-1 ----
        if (pf) { STAGE(4, nxt, koff); STAGE(5, nxt, koff); }
#pragma unroll
        for (int i = 0; i < 4; i++) {
            a_h[i] = *(const bf16x8*)(raH + cur*BUFS + (4+i)*512);
            a_l[i] = *(const bf16x8*)(raL + cur*BUFS + (4+i)*512);
        }
        __builtin_amdgcn_s_barrier();
        __builtin_amdgcn_s_setprio(1);
#pragma unroll
        for (int i = 0; i < 4; i++)
#pragma unroll
            for (int j = 0; j < 2; j++) TRIPLE(4+i, j, a_h[i], a_l[i], b_h[j], b_l[j]);
        __builtin_amdgcn_s_setprio(0);
        __builtin_amdgcn_s_barrier();

        // ---- phase 3: MFMA i4-7 x j2-3 ----
        if (pf) { STAGE(6, nxt, koff); STAGE(7, nxt, koff); }
        __builtin_amdgcn_s_barrier();
        __builtin_amdgcn_s_setprio(1);
#pragma unroll
        for (int i = 0; i < 4; i++)
#pragma unroll
            for (int j = 0; j < 2; j++) TRIPLE(4+i, 2+j, a_h[i], a_l[i], b_h[2+j], b_l[2+j]);
        __builtin_amdgcn_s_setprio(0);
        __builtin_amdgcn_s_barrier();
    }

    if (!FUSE) {
        // store epilogue: relu + split2 -> Ch/Cl planes
#pragma unroll
        for (int i = 0; i < 8; i++)
#pragma unroll
            for (int j = 0; j < 4; j++) {
                int col = n0 + wc*64 + j*16 + fm;
                float bs = bias[col];
#pragma unroll
                for (int r2 = 0; r2 < 4; r2++) {
                    int row = m0 + wr*128 + i*16 + kg*4 + r2;
                    float v = fmaxf(acc[i][j][r2] + bs, 0.f);
                    short h, l; split2(v, h, l);
                    Ch[(size_t)row * ldc + col] = h;
                    Cl[(size_t)row * ldc + col] = l;
                }
            }
    } else {
        // fused logits epilogue: two 128-row passes through LDS.
        // LDS: u32[128][256], word = (hi<<16)|lo of split2(relu(acc+b)),
        // col swizzled by ((localrow&15)<<1).
        unsigned* L32 = (unsigned*)&P[0][0][0][0];
#pragma unroll
        for (int h = 0; h < 2; h++) {
            if (wr == h) {
#pragma unroll
                for (int i = 0; i < 8; i++)
#pragma unroll
                    for (int j = 0; j < 4; j++) {
                        int col = wc*64 + j*16 + fm;
                        float bs = bias[n0 + col];
#pragma unroll
                        for (int r2 = 0; r2 < 4; r2++) {
                            int lr = i*16 + kg*4 + r2;
                            float v = fmaxf(acc[i][j][r2] + bs, 0.f);
                            short sh, sl; split2(v, sh, sl);
                            L32[lr*256 + (col ^ ((lr & 15) << 1))] =
                                ((unsigned)(unsigned short)sh << 16) | (unsigned short)sl;
                        }
                    }
            }
            __syncthreads();
            f32x4 pl0 = {}, pl1 = {};
            int rbase = (wv*16 + fm) * 256;
            int swr = fm << 1;
#pragma unroll
            for (int s = 0; s < 8; s++) {
                int kb = s*32 + kg*8;
                bf16x8 A_h, A_l;
#pragma unroll
                for (int c = 0; c < 8; c++) {
                    unsigned u = L32[rbase + ((kb + c) ^ swr)];
                    A_h[c] = (short)(u >> 16);
                    A_l[c] = (short)(u & 0xffffu);
                }
                size_t wk = (size_t)(n0 + kb);
                bf16x8 B0h = *(const bf16x8*)&W3h[(size_t)fm * H_ + wk];
                bf16x8 B0l = *(const bf16x8*)&W3l[(size_t)fm * H_ + wk];
                bf16x8 B1h = *(const bf16x8*)&W3h[(size_t)(16 + fm) * H_ + wk];
                bf16x8 B1l = *(const bf16x8*)&W3l[(size_t)(16 + fm) * H_ + wk];
                pl0 = __builtin_amdgcn_mfma_f32_16x16x32_bf16(A_l, B0h, pl0, 0, 0, 0);
                pl0 = __builtin_amdgcn_mfma_f32_16x16x32_bf16(A_h, B0l, pl0, 0, 0, 0);
                pl0 = __builtin_amdgcn_mfma_f32_16x16x32_bf16(A_h, B0h, pl0, 0, 0, 0);
                pl1 = __builtin_amdgcn_mfma_f32_16x16x32_bf16(A_l, B1h, pl1, 0, 0, 0);
                pl1 = __builtin_amdgcn_mfma_f32_16x16x32_bf16(A_h, B1l, pl1, 0, 0, 0);
                pl1 = __builtin_amdgcn_mfma_f32_16x16x32_bf16(A_h, B1h, pl1, 0, 0, 0);
            }
            int growb = m0c + m0 + h*128 + wv*16 + kg*4;
#pragma unroll
            for (int r2 = 0; r2 < 4; r2++)
                atomicAdd(&logit_acc[(size_t)(growb + r2) * NRES + fm], pl0[r2]);
            if (fm < 4) {
#pragma unroll
                for (int r2 = 0; r2 < 4; r2++)
                    atomicAdd(&logit_acc[(size_t)(growb + r2) * NRES + 16 + fm], pl1[r2]);
            }
            __syncthreads();
        }
    }
#undef STAGE
#undef TRIPLE
}

// ---------------- argmax: bias + argmax + mask over atomically-summed logits ----
__global__ __launch_bounds__(256) void argmax_kernel(
    float* __restrict__ logits, const float* __restrict__ b3,
    const int* __restrict__ fixed_mask, const int* __restrict__ seq_t,
    float* __restrict__ seq_out, int* __restrict__ seq_int, int m0c)
{
    int grow = m0c + blockIdx.x * 256 + threadIdx.x;
    float* lg = logits + (size_t)grow * NRES;
    float best = -1e30f; int bi = 0;
#pragma unroll
    for (int n = 0; n < NRES; n++) {
        float s = lg[n] + b3[n];
        lg[n] = s;
        if (s > best) { best = s; bi = n; }
    }
    int fmk = fixed_mask[grow];
    int sv = fmk ? seq_t[grow] : bi;
    seq_int[grow] = sv;
    seq_out[grow] = (float)sv;
}

// ---------------- geometry, atom-parallel: one thread per (point, atom14) ------
// 458752 threads (1792 blocks) vs the old 32768 (2 waves/CU, latency-bound).
// Each thread recomputes rb + ONLY its group's frame chain, with op order
// identical to the reference composition sequence (bit-exact fp32).
__global__ __launch_bounds__(256) void geom_atom_kernel(
    const float* __restrict__ angles, const float* __restrict__ rigids,
    const int* __restrict__ seq0i,
    const float* __restrict__ dframes, const int* __restrict__ gidx,
    const float* __restrict__ a14m, const float* __restrict__ litp,
    float* __restrict__ out_pred, float* __restrict__ out_m14)
{
    __shared__ float sdf[NTAB*8*16];
    __shared__ int   sgi[NTAB*14];
    __shared__ float sm14[NTAB*14];
    __shared__ float slit[NTAB*14*3];
    for (int i = threadIdx.x; i < NTAB*128; i += 256) sdf[i] = dframes[i];
    for (int i = threadIdx.x; i < NTAB*14; i += 256) { sgi[i] = gidx[i]; sm14[i] = a14m[i]; }
    for (int i = threadIdx.x; i < NTAB*42; i += 256) slit[i] = litp[i];
    __syncthreads();

    int idx = blockIdx.x * 256 + threadIdx.x;    // p*14 + a
    int p = idx / 14, a = idx - p * 14;
    int s = seq0i[p];

    const float* rg = rigids + (size_t)p * 7;
    float qw = rg[0], qx = rg[1], qy = rg[2], qz = rg[3];
    float tbx = rg[4], tby = rg[5], tbz = rg[6];
    float qn = 1.0f / sqrtf(qw*qw + qx*qx + qy*qy + qz*qz + 1e-8f);
    qw *= qn; qx *= qn; qy *= qn; qz *= qn;
    float rb[9];
    rb[0] = 1.f - 2.f*(qy*qy + qz*qz); rb[1] = 2.f*(qx*qy - qw*qz); rb[2] = 2.f*(qx*qz + qw*qy);
    rb[3] = 2.f*(qx*qy + qw*qz); rb[4] = 1.f - 2.f*(qx*qx + qz*qz); rb[5] = 2.f*(qy*qz - qw*qx);
    rb[6] = 2.f*(qx*qz - qw*qy); rb[7] = 2.f*(qy*qz + qw*qx); rb[8] = 1.f - 2.f*(qx*qx + qy*qy);

    const float* ang = angles + (size_t)p * 14;
    int g = sgi[s*14 + a];

    // local torsion frame builder (same op order as reference)
    auto build = [&](int gg, float* r, float* t) {
        const float* df = &sdf[(s*8 + gg)*16];
        float c, sn;
        if (gg == 0) { c = 1.f; sn = 0.f; }
        else { sn = ang[(gg-1)*2 + 0]; c = ang[(gg-1)*2 + 1]; }
#pragma unroll
        for (int i = 0; i < 3; i++) {
            float d0 = df[i*4+0], d1 = df[i*4+1], d2 = df[i*4+2];
            r[i*3+0] = d0;
            r[i*3+1] = d1*c + d2*sn;
            r[i*3+2] = d2*c - d1*sn;
            t[i] = df[i*4+3];
        }
    };

    float R[9], T[3];
    if (g < 5) {
        build(g, R, T);
    } else {
        build(4, R, T);
        for (int gg = 5; gg <= g; gg++) {
            float f[9], tt[3], r2[9], t2[3];
            build(gg, f, tt);
#pragma unroll
            for (int i = 0; i < 3; i++) {
#pragma unroll
                for (int j = 0; j < 3; j++)
                    r2[i*3+j] = R[i*3+0]*f[0*3+j] + R[i*3+1]*f[1*3+j] + R[i*3+2]*f[2*3+j];
                t2[i] = R[i*3+0]*tt[0] + R[i*3+1]*tt[1] + R[i*3+2]*tt[2] + T[i];
            }
#pragma unroll
            for (int i = 0; i < 9; i++) R[i] = r2[i];
#pragma unroll
            for (int i = 0; i < 3; i++) T[i] = t2[i];
        }
    }

    // global compose (same op order as reference)
    float Rg[9], Tg[3];
#pragma unroll
    for (int i = 0; i < 3; i++) {
#pragma unroll
        for (int j = 0; j < 3; j++)
            Rg[i*3+j] = rb[i*3+0]*R[0*3+j] + rb[i*3+1]*R[1*3+j] + rb[i*3+2]*R[2*3+j];
        Tg[i] = rb[i*3+0]*T[0] + rb[i*3+1]*T[1] + rb[i*3+2]*T[2];
    }
    Tg[0] += tbx; Tg[1] += tby; Tg[2] += tbz;

    float m  = sm14[s*14 + a];
    float lx = slit[(s*14 + a)*3 + 0];
    float ly = slit[(s*14 + a)*3 + 1];
    float lz = slit[(s*14 + a)*3 + 2];
    out_pred[(size_t)idx*3 + 0] = (Rg[0]*lx + Rg[1]*ly + Rg[2]*lz + Tg[0]) * m;
    out_pred[(size_t)idx*3 + 1] = (Rg[3]*lx + Rg[4]*ly + Rg[5]*lz + Tg[1]) * m;
    out_pred[(size_t)idx*3 + 2] = (Rg[6]*lx + Rg[7]*ly + Rg[8]*lz + Tg[2]) * m;
    out_m14[idx] = m;
}

// ---------------- final gather: one thread per (point, atom37) ----------------
__global__ __launch_bounds__(256) void final_gather_kernel(
    const int* __restrict__ seq0i, const int* __restrict__ residx,
    const float* __restrict__ a37m, const float* __restrict__ out_pred,
    float* __restrict__ out_final, float* __restrict__ out_m37)
{
    __shared__ float sm37[NTAB*37];
    for (int i = threadIdx.x; i < NTAB*37; i += 256) sm37[i] = a37m[i];
    __syncthreads();

    int idx = blockIdx.x * 256 + threadIdx.x;    // p*37 + a
    int p = idx / 37, a = idx - p * 37;
    int s = seq0i[p];
    int id = residx[idx];
    const float* src = out_pred + ((size_t)p*14 + id)*3;
    out_final[(size_t)idx*3 + 0] = src[0];
    out_final[(size_t)idx*3 + 1] = src[1];
    out_final[(size_t)idx*3 + 2] = src[2];
    out_m37[idx] = sm37[s*37 + a];
}

extern "C" void kernel_launch(void* const* d_in, const int* in_sizes, int n_in,
                              void* d_out, int out_size, void* d_ws, size_t ws_size,
                              hipStream_t stream) {
    const float* act        = (const float*)d_in[0];
    const float* angles     = (const float*)d_in[1];
    const float* rigids     = (const float*)d_in[2];
    const int*   fixed_mask = (const int*)d_in[3];
    const int*   seq_t      = (const int*)d_in[4];
    const int*   residx     = (const int*)d_in[5];
    const float* lng        = (const float*)d_in[6];
    const float* lnb        = (const float*)d_in[7];
    const float* w1         = (const float*)d_in[8];
    const float* b1         = (const float*)d_in[9];
    const float* w2         = (const float*)d_in[10];
    const float* b2         = (const float*)d_in[11];
    const float* w3         = (const float*)d_in[12];
    const float* b3         = (const float*)d_in[13];
    const float* dfr        = (const float*)d_in[14];
    const int*   gidx       = (const int*)d_in[15];
    const float* a14m       = (const float*)d_in[16];
    const float* a37m       = (const float*)d_in[17];
    const float* litp       = (const float*)d_in[18];

    float* out        = (float*)d_out;
    float* out_logits = out;
    float* out_seq    = out_logits + (size_t)M_TOTAL * NRES;
    float* out_pred   = out_seq    + (size_t)M_TOTAL;
    float* out_final  = out_pred   + (size_t)M_TOTAL * 42;
    float* out_m14    = out_final  + (size_t)M_TOTAL * 111;
    float* out_m37    = out_m14    + (size_t)M_TOTAL * 14;

    char* wsp = (char*)d_ws;
    int*   seq0i = (int*)wsp;   wsp += (size_t)M_TOTAL * sizeof(int);
    short* w1h   = (short*)wsp; wsp += (size_t)H_ * C_ * sizeof(short);
    short* w1l   = (short*)wsp; wsp += (size_t)H_ * C_ * sizeof(short);
    short* w2h   = (short*)wsp; wsp += (size_t)H_ * H_ * sizeof(short);
    short* w2l   = (short*)wsp; wsp += (size_t)H_ * H_ * sizeof(short);
    short* w3h   = (short*)wsp; wsp += (size_t)128 * H_ * sizeof(short);
    short* w3l   = (short*)wsp; wsp += (size_t)128 * H_ * sizeof(short);
    short* Xh    = (short*)wsp; wsp += (size_t)M_TOTAL * C_ * sizeof(short);
    short* Xl    = (short*)wsp; wsp += (size_t)M_TOTAL * C_ * sizeof(short);

    size_t fixed_bytes = (size_t)(wsp - (char*)d_ws);
    size_t per_row = 2ull * H_ * sizeof(short);   // H1h/H1l only (H2 eliminated)
    size_t avail = ws_size - fixed_bytes;
    int chunkM = 4096;
    if (avail >= (size_t)M_TOTAL * per_row)      chunkM = M_TOTAL;
    else if (avail >= 16384ull * per_row)        chunkM = 16384;
    else if (avail >= 8192ull * per_row)         chunkM = 8192;

    short* H1h = (short*)wsp; wsp += (size_t)chunkM * H_ * sizeof(short);
    short* H1l = (short*)wsp;

    // logits accumulated via atomics into out_logits -> zero it first
    hipMemsetAsync(out_logits, 0, (size_t)M_TOTAL * NRES * sizeof(float), stream);

    conv_w_kernel<<<dim3(H_/32, C_/32), 256, 0, stream>>>(w1, w1h, w1l, C_, H_, H_);
    conv_w_kernel<<<dim3(H_/32, H_/32), 256, 0, stream>>>(w2, w2h, w2l, H_, H_, H_);
    conv_w_kernel<<<dim3(128/32, H_/32), 256, 0, stream>>>(w3, w3h, w3l, H_, NRES, 128);

    ln_split_kernel<<<M_TOTAL/4, 256, 0, stream>>>(act, lng, lnb, Xh, Xl);

    for (int c = 0; c < M_TOTAL / chunkM; c++) {
        int m0 = c * chunkM;
        // GEMM1: LN'd act planes @ w1 (K=384) -> H1 planes
        presplit_gemm256<false><<<dim3(chunkM/256, H_/256), 512, 0, stream>>>(
            Xh + (size_t)m0 * C_, Xl + (size_t)m0 * C_, w1h, w1l, b1,
            H1h, H1l, C_, H_, nullptr, nullptr, nullptr, 0);
        // GEMM2: H1 @ w2 (K=1024), fused logits epilogue (H2 never stored)
        presplit_gemm256<true><<<dim3(chunkM/256, H_/256), 512, 0, stream>>>(
            H1h, H1l, w2h, w2l, b2,
            nullptr, nullptr, H_, 0, w3h, w3l, out_logits, m0);
        // bias + argmax + mask
        argmax_kernel<<<chunkM/256, 256, 0, stream>>>(
            out_logits, b3, fixed_mask, seq_t, out_seq, seq0i, m0);
    }

    // atom-parallel geometry: 32768*14 threads, then 32768*37 gather
    geom_atom_kernel<<<(M_TOTAL*14)/256, 256, 0, stream>>>(
        angles, rigids, seq0i, dfr, gidx, a14m, litp, out_pred, out_m14);
    final_gather_kernel<<<(M_TOTAL*37)/256, 256, 0, stream>>>(
        seq0i, residx, a37m, out_pred, out_final, out_m37);
}

// Round 9
// 446.529 us; speedup vs baseline: 1.2586x; 1.0303x over previous
//
#include <hip/hip_runtime.h>
#include <math.h>

#define B_ 32
#define N_ 1024
#define C_ 384
#define H_ 1024
#define NRES 20
#define NTAB 21
#define M_TOTAL (B_*N_)   // 32768
#define BK 32

typedef __attribute__((ext_vector_type(8))) short bf16x8;
typedef __attribute__((ext_vector_type(4))) float f32x4;

#define GLOAD_LDS(gptr, lptr) \
    __builtin_amdgcn_global_load_lds( \
        (const __attribute__((address_space(1))) void*)(gptr), \
        (__attribute__((address_space(3))) void*)(lptr), 16, 0, 0)

__device__ inline short bf16_rne(float v) {
    unsigned u = __float_as_uint(v);
    unsigned r = u + 0x7fffu + ((u >> 16) & 1u);
    return (short)(r >> 16);
}
// v ~= hi + lo, each bf16 (RNE). ~16 mantissa bits captured.
__device__ inline void split2(float v, short& h, short& l) {
    unsigned u = __float_as_uint(v);
    unsigned r = (u + 0x7fffu + ((u >> 16) & 1u)) & 0xffff0000u;
    h = (short)(r >> 16);
    l = bf16_rne(v - __uint_as_float(r));
}

// ---------------- conv body (shared by prep_kernel) ----------------
__device__ inline void conv_body(const float* __restrict__ w,
                                 short* __restrict__ th, short* __restrict__ tl,
                                 int K, int N, int n0, int k0,
                                 float (*t)[33]) {
    int tx = threadIdx.x & 31, ty = threadIdx.x >> 5;
#pragma unroll
    for (int i = ty; i < 32; i += 8) {
        int k = k0 + i, n = n0 + tx;
        t[i][tx] = (n < N) ? w[(size_t)k * N + n] : 0.f;
    }
    __syncthreads();
#pragma unroll
    for (int i = ty; i < 32; i += 8) {
        int n = n0 + i, k = k0 + tx;
        short h, l; split2(t[tx][i], h, l);
        th[(size_t)n * K + k] = h;
        tl[(size_t)n * K + k] = l;
    }
}

// ---------------- prep: 3x weight transpose/split + LN/split, one launch -------
// blocks [0,384): w1 (grid 32x12); [384,1408): w2 (32x32); [1408,1536): w3 (4x32);
// [1536, 1536+8192): ln rows (4 rows/block).
__global__ __launch_bounds__(256) void prep_kernel(
    const float* __restrict__ w1, const float* __restrict__ w2,
    const float* __restrict__ w3,
    short* __restrict__ w1h, short* __restrict__ w1l,
    short* __restrict__ w2h, short* __restrict__ w2l,
    short* __restrict__ w3h, short* __restrict__ w3l,
    const float* __restrict__ act, const float* __restrict__ lng,
    const float* __restrict__ lnb,
    short* __restrict__ Xh, short* __restrict__ Xl)
{
    __shared__ float t[32][33];
    int bid = blockIdx.x;
    if (bid < 384) {
        conv_body(w1, w1h, w1l, C_, H_, (bid & 31) * 32, (bid >> 5) * 32, t);
    } else if (bid < 1408) {
        int b = bid - 384;
        conv_body(w2, w2h, w2l, H_, H_, (b & 31) * 32, (b >> 5) * 32, t);
    } else if (bid < 1536) {
        int b = bid - 1408;
        conv_body(w3, w3h, w3l, H_, NRES, (b & 3) * 32, (b >> 2) * 32, t);
    } else {
        int wave = threadIdx.x >> 6;
        int lane = threadIdx.x & 63;
        int row  = (bid - 1536) * 4 + wave;
        const float* x = act + (size_t)row * C_;
        float v[6];
        float s = 0.f;
#pragma unroll
        for (int i = 0; i < 6; i++) { v[i] = x[lane + i*64]; s += v[i]; }
#pragma unroll
        for (int off = 32; off > 0; off >>= 1) s += __shfl_xor(s, off, 64);
        float mu = s * (1.0f/384.0f);
        float vs = 0.f;
#pragma unroll
        for (int i = 0; i < 6; i++) { float d = v[i]-mu; vs += d*d; }
#pragma unroll
        for (int off = 32; off > 0; off >>= 1) vs += __shfl_xor(vs, off, 64);
        float rstd = 1.0f / sqrtf(vs * (1.0f/384.0f) + 1e-5f);
#pragma unroll
        for (int i = 0; i < 6; i++) {
            int col = lane + i*64;
            float y = (v[i] - mu) * rstd * lng[col] + lnb[col];
            short h, l; split2(y, h, l);
            Xh[(size_t)row * C_ + col] = h;
            Xl[(size_t)row * C_ + col] = l;
        }
    }
}

// ---------------- presplit GEMM: 256x256 tile, 8 waves, 4-phase counted-vmcnt ----
// R2 schedule, plain blockIdx mapping (default round-robin co-locates same-A
// blocks per XCD since gridDim.x % 8 == 0).
// FUSE=true (GEMM2): round-trip relu'd split tile through LDS, MFMA vs w3,
// write per-panel logits partials to Pbuf[blockIdx.y][row][32] with PLAIN
// coalesced stores (no atomics -> deterministic; rows unique per block).
// grid: (chunkM/256, H/256), 512 threads.
template<bool FUSE>
__global__ __launch_bounds__(512, 2) void presplit_gemm256(
    const short* __restrict__ Ahg, const short* __restrict__ Alg,
    const short* __restrict__ BTh, const short* __restrict__ BTl,
    const float* __restrict__ bias,
    short* __restrict__ Ch, short* __restrict__ Cl,
    int K, int ldc,
    const short* __restrict__ W3h, const short* __restrict__ W3l,
    float* __restrict__ pbuf, int m0c)
{
    __shared__ short P[4][2][256][32];   // planes {Ah,Al,Bh,Bl} x dbuf, 128 KiB
    const int BUFS = 256*32;             // shorts per buffer within a plane
    int tid = threadIdx.x;
    int m0 = blockIdx.x * 256;
    int n0 = blockIdx.y * 256;
    int lane = tid & 63, wv = tid >> 6;
    int wr = wv >> 2, wc = wv & 3;       // wave grid 2M x 4N -> wave tile 128x64
    int fm = lane & 15, kg = lane >> 4;

    // staging role: wave wv stages plane (wv>>1), row-half (wv&1): 8 DMAs/step
    int pl = wv >> 1, hf = wv & 1;
    const short* gsrc = (pl == 0) ? Ahg : (pl == 1) ? Alg : (pl == 2) ? BTh : BTl;
    int base = (pl < 2) ? m0 : n0;
    // lane l -> LDS slot (row16=l>>2, cb=l&3); fetch global cb ^ swz(row16)
    int swcb = (lane & 3) ^ ((lane >> 3) & 3);
    const short* gp = gsrc + (size_t)(base + hf*128 + (lane >> 2)) * K + swcb * 8;
    short* lpl = &P[pl][0][0][0] + hf * (128*32);

    // swizzled read col-offset (shorts); identical for all frag rows since
    // (row>>1)&3 == (fm>>1)&3 for row = 16*q + fm.
    int sz = (kg ^ ((fm >> 1) & 3)) * 8;
    const short* raH = &P[0][0][wr*128 + fm][0] + sz;
    const short* raL = &P[1][0][wr*128 + fm][0] + sz;
    const short* rbH = &P[2][0][wc*64  + fm][0] + sz;
    const short* rbL = &P[3][0][wc*64  + fm][0] + sz;

#define STAGE(c, bsel, koff) \
    GLOAD_LDS(gp + (size_t)((c)*16) * K + (koff), lpl + (bsel)*BUFS + (c)*512)

#define TRIPLE(ai, aj, AH, AL, BH, BL) { \
    f32x4 cc = acc[ai][aj]; \
    cc = __builtin_amdgcn_mfma_f32_16x16x32_bf16(AL, BH, cc, 0, 0, 0); \
    cc = __builtin_amdgcn_mfma_f32_16x16x32_bf16(AH, BL, cc, 0, 0, 0); \
    cc = __builtin_amdgcn_mfma_f32_16x16x32_bf16(AH, BH, cc, 0, 0, 0); \
    acc[ai][aj] = cc; }

    f32x4 acc[8][4] = {};
    const int NT = K / BK;

    // prologue: stage tile 0 into buffer 0
#pragma unroll
    for (int c = 0; c < 8; c++) STAGE(c, 0, 0);

    for (int t = 0; t < NT; ++t) {
        int cur = t & 1, nxt = cur ^ 1;
        size_t koff = (size_t)(t + 1) * BK;
        bool pf = (t + 1 < NT);

        bf16x8 a_h[4], a_l[4], b_h[4], b_l[4];

        // ---- phase 0: a0-3 + b0-1, MFMA i0-3 x j0-1 ----
        if (pf) {
            STAGE(0, nxt, koff); STAGE(1, nxt, koff);
            asm volatile("s_waitcnt vmcnt(2)" ::: "memory");
        } else {
            asm volatile("s_waitcnt vmcnt(0)" ::: "memory");
        }
        __builtin_amdgcn_s_barrier();
        __builtin_amdgcn_sched_barrier(0);
#pragma unroll
        for (int i = 0; i < 4; i++) {
            a_h[i] = *(const bf16x8*)(raH + cur*BUFS + i*512);
            a_l[i] = *(const bf16x8*)(raL + cur*BUFS + i*512);
        }
#pragma unroll
        for (int j = 0; j < 2; j++) {
            b_h[j] = *(const bf16x8*)(rbH + cur*BUFS + j*512);
            b_l[j] = *(const bf16x8*)(rbL + cur*BUFS + j*512);
        }
        __builtin_amdgcn_s_setprio(1);
#pragma unroll
        for (int i = 0; i < 4; i++)
#pragma unroll
            for (int j = 0; j < 2; j++) TRIPLE(i, j, a_h[i], a_l[i], b_h[j], b_l[j]);
        __builtin_amdgcn_s_setprio(0);
        __builtin_amdgcn_s_barrier();

        // ---- phase 1: b2-3, MFMA i0-3 x j2-3 ----
        if (pf) { STAGE(2, nxt, koff); STAGE(3, nxt, koff); }
#pragma unroll
        for (int j = 0; j < 2; j++) {
            b_h[2+j] = *(const bf16x8*)(rbH + cur*BUFS + (2+j)*512);
            b_l[2+j] = *(const bf16x8*)(rbL + cur*BUFS + (2+j)*512);
        }
        __builtin_amdgcn_s_barrier();
        __builtin_amdgcn_s_setprio(1);
#pragma unroll
        for (int i = 0; i < 4; i++)
#pragma unroll
            for (int j = 0; j < 2; j++) TRIPLE(i, 2+j, a_h[i], a_l[i], b_h[2+j], b_l[2+j]);
        __builtin_amdgcn_s_setprio(0);
        __builtin_amdgcn_s_barrier();

        // ---- phase 2: a4-7, MFMA i4-7 x j0-1 ----
        if (pf) { STAGE(4, nxt, koff); STAGE(5, nxt, koff); }
#pragma unroll
        for (int i = 0; i < 4; i++) {
            a_h[i] = *(const bf16x8*)(raH + cur*BUFS + (4+i)*512);
            a_l[i] = *(const bf16x8*)(raL + cur*BUFS + (4+i)*512);
        }
        __builtin_amdgcn_s_barrier();
        __builtin_amdgcn_s_setprio(1);
#pragma unroll
        for (int i = 0; i < 4; i++)
#pragma unroll
            for (int j = 0; j < 2; j++) TRIPLE(4+i, j, a_h[i], a_l[i], b_h[j], b_l[j]);
        __builtin_amdgcn_s_setprio(0);
        __builtin_amdgcn_s_barrier();

        // ---- phase 3: MFMA i4-7 x j2-3 ----
        if (pf) { STAGE(6, nxt, koff); STAGE(7, nxt, koff); }
        __builtin_amdgcn_s_barrier();
        __builtin_amdgcn_s_setprio(1);
#pragma unroll
        for (int i = 0; i < 4; i++)
#pragma unroll
            for (int j = 0; j < 2; j++) TRIPLE(4+i, 2+j, a_h[i], a_l[i], b_h[2+j], b_l[2+j]);
        __builtin_amdgcn_s_setprio(0);
        __builtin_amdgcn_s_barrier();
    }

    if (!FUSE) {
        // store epilogue: relu + split2 -> Ch/Cl planes
#pragma unroll
        for (int i = 0; i < 8; i++)
#pragma unroll
            for (int j = 0; j < 4; j++) {
                int col = n0 + wc*64 + j*16 + fm;
                float bs = bias[col];
#pragma unroll
                for (int r2 = 0; r2 < 4; r2++) {
                    int row = m0 + wr*128 + i*16 + kg*4 + r2;
                    float v = fmaxf(acc[i][j][r2] + bs, 0.f);
                    short h, l; split2(v, h, l);
                    Ch[(size_t)row * ldc + col] = h;
                    Cl[(size_t)row * ldc + col] = l;
                }
            }
    } else {
        // fused logits epilogue: two 128-row passes through LDS.
        // LDS: u32[128][256], word = (hi<<16)|lo of split2(relu(acc+b)),
        // col swizzled by ((localrow&15)<<1).
        unsigned* L32 = (unsigned*)&P[0][0][0][0];
#pragma unroll
        for (int h = 0; h < 2; h++) {
            if (wr == h) {
#pragma unroll
                for (int i = 0; i < 8; i++)
#pragma unroll
                    for (int j = 0; j < 4; j++) {
                        int col = wc*64 + j*16 + fm;
                        float bs = bias[n0 + col];
#pragma unroll
                        for (int r2 = 0; r2 < 4; r2++) {
                            int lr = i*16 + kg*4 + r2;
                            float v = fmaxf(acc[i][j][r2] + bs, 0.f);
                            short sh, sl; split2(v, sh, sl);
                            L32[lr*256 + (col ^ ((lr & 15) << 1))] =
                                ((unsigned)(unsigned short)sh << 16) | (unsigned short)sl;
                        }
                    }
            }
            __syncthreads();
            f32x4 pl0 = {}, pl1 = {};
            int rbase = (wv*16 + fm) * 256;
            int swr = fm << 1;
#pragma unroll
            for (int s = 0; s < 8; s++) {
                int kb = s*32 + kg*8;
                bf16x8 A_h, A_l;
#pragma unroll
                for (int c = 0; c < 8; c++) {
                    unsigned u = L32[rbase + ((kb + c) ^ swr)];
                    A_h[c] = (short)(u >> 16);
                    A_l[c] = (short)(u & 0xffffu);
                }
                size_t wk = (size_t)(n0 + kb);
                bf16x8 B0h = *(const bf16x8*)&W3h[(size_t)fm * H_ + wk];
                bf16x8 B0l = *(const bf16x8*)&W3l[(size_t)fm * H_ + wk];
                bf16x8 B1h = *(const bf16x8*)&W3h[(size_t)(16 + fm) * H_ + wk];
                bf16x8 B1l = *(const bf16x8*)&W3l[(size_t)(16 + fm) * H_ + wk];
                pl0 = __builtin_amdgcn_mfma_f32_16x16x32_bf16(A_l, B0h, pl0, 0, 0, 0);
                pl0 = __builtin_amdgcn_mfma_f32_16x16x32_bf16(A_h, B0l, pl0, 0, 0, 0);
                pl0 = __builtin_amdgcn_mfma_f32_16x16x32_bf16(A_h, B0h, pl0, 0, 0, 0);
                pl1 = __builtin_amdgcn_mfma_f32_16x16x32_bf16(A_l, B1h, pl1, 0, 0, 0);
                pl1 = __builtin_amdgcn_mfma_f32_16x16x32_bf16(A_h, B1l, pl1, 0, 0, 0);
                pl1 = __builtin_amdgcn_mfma_f32_16x16x32_bf16(A_h, B1h, pl1, 0, 0, 0);
            }
            // per-panel partial store (deterministic, race-free: rows unique)
            int growb = m0c + m0 + h*128 + wv*16 + kg*4;
            float* pp = pbuf + ((size_t)blockIdx.y * M_TOTAL + growb) * 32;
#pragma unroll
            for (int r2 = 0; r2 < 4; r2++)
                pp[(size_t)r2 * 32 + fm] = pl0[r2];
            if (fm < 4) {
#pragma unroll
                for (int r2 = 0; r2 < 4; r2++)
                    pp[(size_t)r2 * 32 + 16 + fm] = pl1[r2];
            }
            __syncthreads();
        }
    }
#undef STAGE
#undef TRIPLE
}

// ---------------- tail: argmax + geometry + gather, fused (16 points/block) ----
__global__ __launch_bounds__(256) void tail_kernel(
    const float* __restrict__ Pbuf, const float* __restrict__ b3,
    const int* __restrict__ fixed_mask, const int* __restrict__ seq_t,
    const float* __restrict__ angles, const float* __restrict__ rigids,
    const int* __restrict__ residx, const float* __restrict__ dframes,
    const int* __restrict__ gidx, const float* __restrict__ a14m,
    const float* __restrict__ a37m, const float* __restrict__ litp,
    float* __restrict__ out_logits, float* __restrict__ out_seq,
    float* __restrict__ out_pred, float* __restrict__ out_final,
    float* __restrict__ out_m14, float* __restrict__ out_m37)
{
    __shared__ float sdf[NTAB*8*16];
    __shared__ int   sgi[NTAB*14];
    __shared__ float sm14[NTAB*14];
    __shared__ float sm37[NTAB*37];
    __shared__ float slit[NTAB*14*3];
    __shared__ float spred[16][14][3];
    __shared__ int   sseq[16];

    for (int i = threadIdx.x; i < NTAB*128; i += 256) sdf[i] = dframes[i];
    for (int i = threadIdx.x; i < NTAB*14; i += 256) { sgi[i] = gidx[i]; sm14[i] = a14m[i]; }
    for (int i = threadIdx.x; i < NTAB*37; i += 256) sm37[i] = a37m[i];
    for (int i = threadIdx.x; i < NTAB*42; i += 256) slit[i] = litp[i];
    __syncthreads();

    int pbase = blockIdx.x * 16;

    // ---- phase A: deterministic 4-panel sum + bias, argmax, mask ----
    if (threadIdx.x < 16) {
        int p = pbase + threadIdx.x;
        float best = -1e30f; int bi = 0;
        float* lg = out_logits + (size_t)p * NRES;
#pragma unroll
        for (int n = 0; n < NRES; n++) {
            float s = b3[n];
#pragma unroll
            for (int k = 0; k < 4; k++)
                s += Pbuf[((size_t)k * M_TOTAL + p) * 32 + n];
            lg[n] = s;
            if (s > best) { best = s; bi = n; }
        }
        int sv = fixed_mask[p] ? seq_t[p] : bi;
        sseq[threadIdx.x] = sv;
        out_seq[p] = (float)sv;
    }
    __syncthreads();

    // ---- phase B: per-atom geometry (identical math to R8 geom_atom) ----
    if (threadIdx.x < 224) {
        int pt = threadIdx.x / 14, a = threadIdx.x % 14;
        int p = pbase + pt;
        int s = sseq[pt];
        int idx = p * 14 + a;

        const float* rg = rigids + (size_t)p * 7;
        float qw = rg[0], qx = rg[1], qy = rg[2], qz = rg[3];
        float tbx = rg[4], tby = rg[5], tbz = rg[6];
        float qn = 1.0f / sqrtf(qw*qw + qx*qx + qy*qy + qz*qz + 1e-8f);
        qw *= qn; qx *= qn; qy *= qn; qz *= qn;
        float rb[9];
        rb[0] = 1.f - 2.f*(qy*qy + qz*qz); rb[1] = 2.f*(qx*qy - qw*qz); rb[2] = 2.f*(qx*qz + qw*qy);
        rb[3] = 2.f*(qx*qy + qw*qz); rb[4] = 1.f - 2.f*(qx*qx + qz*qz); rb[5] = 2.f*(qy*qz - qw*qx);
        rb[6] = 2.f*(qx*qz - qw*qy); rb[7] = 2.f*(qy*qz + qw*qx); rb[8] = 1.f - 2.f*(qx*qx + qy*qy);

        const float* ang = angles + (size_t)p * 14;
        int g = sgi[s*14 + a];

        auto build = [&](int gg, float* r, float* t) {
            const float* df = &sdf[(s*8 + gg)*16];
            float c, sn;
            if (gg == 0) { c = 1.f; sn = 0.f; }
            else { sn = ang[(gg-1)*2 + 0]; c = ang[(gg-1)*2 + 1]; }
#pragma unroll
            for (int i = 0; i < 3; i++) {
                float d0 = df[i*4+0], d1 = df[i*4+1], d2 = df[i*4+2];
                r[i*3+0] = d0;
                r[i*3+1] = d1*c + d2*sn;
                r[i*3+2] = d2*c - d1*sn;
                t[i] = df[i*4+3];
            }
        };

        float R[9], T[3];
        if (g < 5) {
            build(g, R, T);
        } else {
            build(4, R, T);
            for (int gg = 5; gg <= g; gg++) {
                float f[9], tt[3], r2[9], t2[3];
                build(gg, f, tt);
#pragma unroll
                for (int i = 0; i < 3; i++) {
#pragma unroll
                    for (int j = 0; j < 3; j++)
                        r2[i*3+j] = R[i*3+0]*f[0*3+j] + R[i*3+1]*f[1*3+j] + R[i*3+2]*f[2*3+j];
                    t2[i] = R[i*3+0]*tt[0] + R[i*3+1]*tt[1] + R[i*3+2]*tt[2] + T[i];
                }
#pragma unroll
                for (int i = 0; i < 9; i++) R[i] = r2[i];
#pragma unroll
                for (int i = 0; i < 3; i++) T[i] = t2[i];
            }
        }

        float Rg[9], Tg[3];
#pragma unroll
        for (int i = 0; i < 3; i++) {
#pragma unroll
            for (int j = 0; j < 3; j++)
                Rg[i*3+j] = rb[i*3+0]*R[0*3+j] + rb[i*3+1]*R[1*3+j] + rb[i*3+2]*R[2*3+j];
            Tg[i] = rb[i*3+0]*T[0] + rb[i*3+1]*T[1] + rb[i*3+2]*T[2];
        }
        Tg[0] += tbx; Tg[1] += tby; Tg[2] += tbz;

        float m  = sm14[s*14 + a];
        float lx = slit[(s*14 + a)*3 + 0];
        float ly = slit[(s*14 + a)*3 + 1];
        float lz = slit[(s*14 + a)*3 + 2];
        float px = (Rg[0]*lx + Rg[1]*ly + Rg[2]*lz + Tg[0]) * m;
        float py = (Rg[3]*lx + Rg[4]*ly + Rg[5]*lz + Tg[1]) * m;
        float pz = (Rg[6]*lx + Rg[7]*ly + Rg[8]*lz + Tg[2]) * m;
        out_pred[(size_t)idx*3 + 0] = px;
        out_pred[(size_t)idx*3 + 1] = py;
        out_pred[(size_t)idx*3 + 2] = pz;
        spred[pt][a][0] = px; spred[pt][a][1] = py; spred[pt][a][2] = pz;
        out_m14[idx] = m;
    }
    __syncthreads();

    // ---- phase C: atom37 gather from LDS ----
    for (int i = threadIdx.x; i < 16*37; i += 256) {
        int pt = i / 37, a = i - pt * 37;
        int p = pbase + pt;
        int s = sseq[pt];
        int idx = p * 37 + a;
        int id = residx[idx];
        out_final[(size_t)idx*3 + 0] = spred[pt][id][0];
        out_final[(size_t)idx*3 + 1] = spred[pt][id][1];
        out_final[(size_t)idx*3 + 2] = spred[pt][id][2];
        out_m37[idx] = sm37[s*37 + a];
    }
}

extern "C" void kernel_launch(void* const* d_in, const int* in_sizes, int n_in,
                              void* d_out, int out_size, void* d_ws, size_t ws_size,
                              hipStream_t stream) {
    const float* act        = (const float*)d_in[0];
    const float* angles     = (const float*)d_in[1];
    const float* rigids     = (const float*)d_in[2];
    const int*   fixed_mask = (const int*)d_in[3];
    const int*   seq_t      = (const int*)d_in[4];
    const int*   residx     = (const int*)d_in[5];
    const float* lng        = (const float*)d_in[6];
    const float* lnb        = (const float*)d_in[7];
    const float* w1         = (const float*)d_in[8];
    const float* b1         = (const float*)d_in[9];
    const float* w2         = (const float*)d_in[10];
    const float* b2         = (const float*)d_in[11];
    const float* w3         = (const float*)d_in[12];
    const float* b3         = (const float*)d_in[13];
    const float* dfr        = (const float*)d_in[14];
    const int*   gidx       = (const int*)d_in[15];
    const float* a14m       = (const float*)d_in[16];
    const float* a37m       = (const float*)d_in[17];
    const float* litp       = (const float*)d_in[18];

    float* out        = (float*)d_out;
    float* out_logits = out;
    float* out_seq    = out_logits + (size_t)M_TOTAL * NRES;
    float* out_pred   = out_seq    + (size_t)M_TOTAL;
    float* out_final  = out_pred   + (size_t)M_TOTAL * 42;
    float* out_m14    = out_final  + (size_t)M_TOTAL * 111;
    float* out_m37    = out_m14    + (size_t)M_TOTAL * 14;

    char* wsp = (char*)d_ws;
    short* w1h   = (short*)wsp; wsp += (size_t)H_ * C_ * sizeof(short);
    short* w1l   = (short*)wsp; wsp += (size_t)H_ * C_ * sizeof(short);
    short* w2h   = (short*)wsp; wsp += (size_t)H_ * H_ * sizeof(short);
    short* w2l   = (short*)wsp; wsp += (size_t)H_ * H_ * sizeof(short);
    short* w3h   = (short*)wsp; wsp += (size_t)128 * H_ * sizeof(short);
    short* w3l   = (short*)wsp; wsp += (size_t)128 * H_ * sizeof(short);
    short* Xh    = (short*)wsp; wsp += (size_t)M_TOTAL * C_ * sizeof(short);
    short* Xl    = (short*)wsp; wsp += (size_t)M_TOTAL * C_ * sizeof(short);

    size_t fixed_bytes = (size_t)(wsp - (char*)d_ws);
    size_t per_row = 2ull * H_ * sizeof(short);   // H1h/H1l only
    size_t PB = 4ull * M_TOTAL * 32 * sizeof(float);  // 16.8 MB partials
    size_t avail = ws_size - fixed_bytes;
    int chunkM;
    if (avail >= (size_t)M_TOTAL * per_row)           chunkM = M_TOTAL;
    else if (avail >= 16384ull * per_row + PB)        chunkM = 16384;
    else if (avail >= 8192ull * per_row + PB)         chunkM = 8192;
    else                                              chunkM = 4096;

    short* H1h = (short*)wsp; wsp += (size_t)chunkM * H_ * sizeof(short);
    short* H1l = (short*)wsp; wsp += (size_t)chunkM * H_ * sizeof(short);
    // Pbuf: aliases dead Xh when single-chunk (GEMM2 runs strictly after the
    // only GEMM1); otherwise placed after H1 planes.
    float* Pbuf = (chunkM == M_TOTAL) ? (float*)Xh : (float*)wsp;

    // 1) prep: 3x weight conv + LN, one launch
    prep_kernel<<<1536 + M_TOTAL/4, 256, 0, stream>>>(
        w1, w2, w3, w1h, w1l, w2h, w2l, w3h, w3l, act, lng, lnb, Xh, Xl);

    for (int c = 0; c < M_TOTAL / chunkM; c++) {
        int m0 = c * chunkM;
        // 2) GEMM1: LN'd act planes @ w1 (K=384) -> H1 planes
        presplit_gemm256<false><<<dim3(chunkM/256, H_/256), 512, 0, stream>>>(
            Xh + (size_t)m0 * C_, Xl + (size_t)m0 * C_, w1h, w1l, b1,
            H1h, H1l, C_, H_, nullptr, nullptr, nullptr, 0);
        // 3) GEMM2: H1 @ w2 (K=1024), fused logits-partial epilogue
        presplit_gemm256<true><<<dim3(chunkM/256, H_/256), 512, 0, stream>>>(
            H1h, H1l, w2h, w2l, b2,
            nullptr, nullptr, H_, 0, w3h, w3l, Pbuf, m0);
    }

    // 4) tail: argmax + geometry + gather, 16 points/block
    tail_kernel<<<M_TOTAL/16, 256, 0, stream>>>(
        Pbuf, b3, fixed_mask, seq_t, angles, rigids, residx,
        dfr, gidx, a14m, a37m, litp,
        out_logits, out_seq, out_pred, out_final, out_m14, out_m37);
}